// Round 28
// baseline (391.916 us; speedup 1.0000x reference)
//
#include <hip/hip_runtime.h>

#define NN 60000
#define NE 300000
#define PB 768
typedef unsigned short ush;
typedef __attribute__((ext_vector_type(8))) short bf16x8;
typedef __attribute__((ext_vector_type(4))) float f32x4;

static inline int cdiv(int a, int b) { return (a + b - 1) / b; }

__device__ inline unsigned ord_enc(float x) {
  unsigned u = __float_as_uint(x);
  return (u & 0x80000000u) ? ~u : (u | 0x80000000u);
}
__device__ inline float ord_dec(unsigned u) {
  return __uint_as_float((u & 0x80000000u) ? (u & 0x7fffffffu) : ~u);
}
__device__ inline float bf2f(unsigned u16) { return __uint_as_float(u16 << 16); }
__device__ inline ush f2bf(float x) {
  unsigned u = __float_as_uint(x);
  return (ush)((u + 0x7FFFu + ((u >> 16) & 1u)) >> 16);
}
__device__ inline unsigned pack2(float lo, float hi) {
  return ((unsigned)f2bf(hi) << 16) | (unsigned)f2bf(lo);
}
__device__ inline void unp8(uint4 u, float* f) {
  f[0] = bf2f(u.x & 0xffff); f[1] = bf2f(u.x >> 16);
  f[2] = bf2f(u.y & 0xffff); f[3] = bf2f(u.y >> 16);
  f[4] = bf2f(u.z & 0xffff); f[5] = bf2f(u.z >> 16);
  f[6] = bf2f(u.w & 0xffff); f[7] = bf2f(u.w >> 16);
}

// ================= CSR build (dst-sorted) =================
__global__ void deg_kernel(const int* __restrict__ key, int* __restrict__ deg) {
  int e = blockIdx.x * blockDim.x + threadIdx.x;
  if (e < NE) atomicAdd(deg + key[e], 1);
}

__global__ void scan1_kernel(const int* __restrict__ deg, int* __restrict__ rowptr,
                             int* __restrict__ partial) {
  __shared__ int s[256];
  int i = blockIdx.x * 256 + threadIdx.x;
  int v = (i < NN) ? deg[i] : 0;
  s[threadIdx.x] = v;
  __syncthreads();
  for (int off = 1; off < 256; off <<= 1) {
    int t = (threadIdx.x >= off) ? s[threadIdx.x - off] : 0;
    __syncthreads();
    s[threadIdx.x] += t;
    __syncthreads();
  }
  if (i < NN) rowptr[i] = s[threadIdx.x] - v;
  if (threadIdx.x == 255) partial[blockIdx.x] = s[255];
}

__global__ void scan2_kernel(int* __restrict__ partial, int nb) {
  __shared__ int s[256];
  int v = (threadIdx.x < nb) ? partial[threadIdx.x] : 0;
  s[threadIdx.x] = v;
  __syncthreads();
  for (int off = 1; off < 256; off <<= 1) {
    int t = (threadIdx.x >= off) ? s[threadIdx.x - off] : 0;
    __syncthreads();
    s[threadIdx.x] += t;
    __syncthreads();
  }
  if (threadIdx.x < nb) partial[threadIdx.x] = s[threadIdx.x] - v;
}

__global__ void scan3_kernel(int* __restrict__ rowptr, const int* __restrict__ partial,
                             int* __restrict__ cursor) {
  int i = blockIdx.x * 256 + threadIdx.x;
  if (i < NN) {
    int r = rowptr[i] + partial[blockIdx.x];
    rowptr[i] = r;
    cursor[i] = r;
  }
}

// scatter + ef permutation fused; emits ef16 (NEx16 bf16) + packed (src,dst) int2
__global__ void scatter_dst_kernel(const int* __restrict__ src, const int* __restrict__ dst,
                                   const float* __restrict__ ef, int* __restrict__ cursor,
                                   int2* __restrict__ sd_s, ush* __restrict__ ef16) {
  int e = blockIdx.x * blockDim.x + threadIdx.x;
  if (e >= NE) return;
  int d = dst[e];
  int j = atomicAdd(cursor + d, 1);
  sd_s[j] = make_int2(src[e], d);
  const float4* ep = (const float4*)(ef + (size_t)e * 16);
  float4 a = ep[0], b = ep[1], c = ep[2], dd = ep[3];
  uint4* bp = (uint4*)(ef16 + (size_t)j * 16);
  uint4 p0, p1;
  p0.x = pack2(a.x, a.y); p0.y = pack2(a.z, a.w);
  p0.z = pack2(b.x, b.y); p0.w = pack2(b.z, b.w);
  p1.x = pack2(c.x, c.y); p1.y = pack2(c.z, c.w);
  p1.z = pack2(dd.x, dd.y); p1.w = pack2(dd.z, dd.w);
  bp[0] = p0; bp[1] = p1;
}

// ---------------- fold: precompute folded weight products (7424 dots of length 64) -------
__global__ void fold_kernel(const float* __restrict__ fp_w, const float* __restrict__ fp_b,
                            const float* __restrict__ ep_w, const float* __restrict__ ep_b,
                            const float* __restrict__ fij, const float* __restrict__ ebias,
                            const float* __restrict__ ni, const float* __restrict__ nj,
                            const float* __restrict__ node, float* __restrict__ fold) {
  int t = blockIdx.x * blockDim.x + threadIdx.x;
  if (t >= 7424) return;
  int o = t & 63;
  const float* A;
  const float* B;
  float init = 0.f;
  if (t < 1024)      { A = ep_w + (size_t)(t >> 6) * 64; B = fij + o; }
  else if (t < 1088) { A = ep_b; B = fij + o; init = ebias[o]; }
  else if (t < 3136) { A = fp_w + (size_t)((t - 1088) >> 6) * 64; B = ni + o; }
  else if (t < 5184) { A = fp_w + (size_t)((t - 3136) >> 6) * 64; B = nj + o; }
  else if (t < 7232) { A = fp_w + (size_t)((t - 5184) >> 6) * 64; B = node + o; }
  else if (t < 7296) { A = fp_b; B = ni + o; }
  else if (t < 7360) { A = fp_b; B = nj + o; }
  else               { A = fp_b; B = node + o; }
  float a = init;
  for (int i = 0; i < 64; ++i) a = fmaf(A[i], B[(size_t)i * 64], a);
  fold[t] = a;
}

// ---------------- merged prep: fold1_frag | nnwt | fij | hproj_frag | face16 -------------
// index ranges (all multiples of 256 -> no intra-block divergence):
// [0,8192) fold1_frag ; [8192,25600) nnwt ; [25600,29696) fij ;
// [29696,41984) hproj_frag ; [41984,521984) face16
__global__ void prep_rest_kernel(const float* __restrict__ fold, const float* __restrict__ nn_w,
                                 const float* __restrict__ nn_b, const float* __restrict__ fij,
                                 const float* __restrict__ ni, const float* __restrict__ nj,
                                 const float* __restrict__ node, const float* __restrict__ face,
                                 ush* __restrict__ Wf1frag, ush* __restrict__ WfragH1,
                                 ush* __restrict__ Wfrag, ush* __restrict__ Wfrag2,
                                 ush* __restrict__ WfragH, ush* __restrict__ face16) {
  int t = blockIdx.x * blockDim.x + threadIdx.x;
  if (t < 8192) {
    if (t < 2048) {
      int i = t & 7, lane = (t >> 3) & 63, ct = t >> 9;
      int k = (lane >> 4) * 8 + i;
      int o = ct * 16 + (lane & 15);
      Wf1frag[t] = (k < 16) ? f2bf(fold[(size_t)k * 64 + o]) : 0;
    } else {
      int idx = t - 2048;
      int i = idx & 7, lane = (idx >> 3) & 63, ct = (idx >> 9) & 3, m = idx >> 11;
      int k = (lane >> 4) * 8 + i;
      int o = ct * 16 + (lane & 15);
      WfragH1[idx] = f2bf(fold[1088 + (size_t)m * 2048 + (size_t)k * 64 + o]);
    }
  } else if (t < 25600) {
    int u = t - 8192;
    int i = u & 7, lane = (u >> 3) & 63, ct = (u >> 9) & 1, kk = u >> 10;
    int k = kk * 32 + (lane >> 4) * 8 + i;
    int o = ct * 16 + (lane & 15);
    float v = (k < 512) ? nn_w[(size_t)(k >> 5) * 1024 + (k & 31) * 32 + o]
                        : nn_b[(k - 512) * 32 + o];
    Wfrag[u] = f2bf(v);
  } else if (t < 29696) {
    int u = t - 25600;
    int i = u & 7, lane = (u >> 3) & 63, ct = (u >> 9) & 3, kk = u >> 11;
    int k = kk * 32 + (lane >> 4) * 8 + i;
    int o = ct * 16 + (lane & 15);
    Wfrag2[u] = f2bf(fij[(size_t)k * 64 + o]);
  } else if (t < 41984) {
    int u = t - 29696;
    int i = u & 7, lane = (u >> 3) & 63, ct = (u >> 9) & 3, kk = (u >> 11) & 1, m = u >> 12;
    int k = kk * 32 + (lane >> 4) * 8 + i;
    int o = ct * 16 + (lane & 15);
    const float* W = (m == 0) ? ni : (m == 1) ? nj : node;
    WfragH[u] = f2bf(W[(size_t)k * 64 + o]);
  } else if (t < 41984 + NN * 8) {
    int u = t - 41984;
    const float4 v = ((const float4*)face)[u];
    ((uint2*)face16)[u] = make_uint2(pack2(v.x, v.y), pack2(v.z, v.w));
  }
}

// ---------------- layer-1 hproj via MFMA: face16(NNx32) @ folded {ni,nj,node}(32x64) -----
__global__ __launch_bounds__(256, 4) void mfma_hproj1_kernel(
    const ush* __restrict__ face16, const ush* __restrict__ WfragH1,
    const float* __restrict__ fold, ush* __restrict__ hs, ush* __restrict__ hd,
    ush* __restrict__ hn) {
  int wave = (blockIdx.x * blockDim.x + threadIdx.x) >> 6;
  int lane = threadIdx.x & 63;
  int m0 = wave * 16;
  if (m0 >= NN) return;
  int arow = lane & 15;
  int aoff = (lane >> 4) * 8;
  bf16x8 a = *(const bf16x8*)(face16 + (size_t)(m0 + arow) * 32 + aoff);
  int ccol = lane & 15;
  int crow = (lane >> 4) * 4;
#pragma unroll
  for (int m = 0; m < 3; ++m) {
    const ush* wm = WfragH1 + (size_t)m * 2048 + lane * 8;
    bf16x8 b0 = *(const bf16x8*)(wm + 0 * 512);
    bf16x8 b1 = *(const bf16x8*)(wm + 1 * 512);
    bf16x8 b2 = *(const bf16x8*)(wm + 2 * 512);
    bf16x8 b3 = *(const bf16x8*)(wm + 3 * 512);
    f32x4 acc0 = {0.f, 0.f, 0.f, 0.f};
    f32x4 acc1 = {0.f, 0.f, 0.f, 0.f};
    f32x4 acc2 = {0.f, 0.f, 0.f, 0.f};
    f32x4 acc3 = {0.f, 0.f, 0.f, 0.f};
    acc0 = __builtin_amdgcn_mfma_f32_16x16x32_bf16(a, b0, acc0, 0, 0, 0);
    acc1 = __builtin_amdgcn_mfma_f32_16x16x32_bf16(a, b1, acc1, 0, 0, 0);
    acc2 = __builtin_amdgcn_mfma_f32_16x16x32_bf16(a, b2, acc2, 0, 0, 0);
    acc3 = __builtin_amdgcn_mfma_f32_16x16x32_bf16(a, b3, acc3, 0, 0, 0);
    float bv0 = fold[7232 + m * 64 + ccol];
    float bv1 = fold[7232 + m * 64 + 16 + ccol];
    float bv2 = fold[7232 + m * 64 + 32 + ccol];
    float bv3 = fold[7232 + m * 64 + 48 + ccol];
    ush* outm = (m == 0) ? hs : (m == 1) ? hd : hn;
#pragma unroll
    for (int j = 0; j < 4; ++j) {
      ush* op = outm + (size_t)(m0 + crow + j) * 64;
      op[ccol] = f2bf(acc0[j] + bv0);
      op[16 + ccol] = f2bf(acc1[j] + bv1);
      op[32 + ccol] = f2bf(acc2[j] + bv2);
      op[48 + ccol] = f2bf(acc3[j] + bv3);
    }
  }
}

// ---------------- layer-1 edge GEMM via MFMA: ef16(NEx16) @ Wf1(32x64, folded, k>=16 = 0) -
__global__ __launch_bounds__(256, 4) void mfma_fout1_kernel(
    const ush* __restrict__ ef16, const ush* __restrict__ Wf1frag, const float* __restrict__ fold,
    const ush* __restrict__ hs, const ush* __restrict__ hd, const int2* __restrict__ sd_s,
    const float* __restrict__ attn, ush* __restrict__ f116, float* __restrict__ logit) {
  int wave = (blockIdx.x * blockDim.x + threadIdx.x) >> 6;
  int lane = threadIdx.x & 63;
  int m0 = wave * 16;
  if (m0 >= NE) return;
  int arow = lane & 15;
  int aoff = (lane >> 4) * 8;
  bf16x8 a = {0, 0, 0, 0, 0, 0, 0, 0};
  if (aoff < 16) a = *(const bf16x8*)(ef16 + (size_t)(m0 + arow) * 16 + aoff);
  const ush* wp = Wf1frag + lane * 8;
  bf16x8 b0 = *(const bf16x8*)(wp + 0 * 512);
  bf16x8 b1 = *(const bf16x8*)(wp + 1 * 512);
  bf16x8 b2 = *(const bf16x8*)(wp + 2 * 512);
  bf16x8 b3 = *(const bf16x8*)(wp + 3 * 512);
  f32x4 acc0 = {0.f, 0.f, 0.f, 0.f};
  f32x4 acc1 = {0.f, 0.f, 0.f, 0.f};
  f32x4 acc2 = {0.f, 0.f, 0.f, 0.f};
  f32x4 acc3 = {0.f, 0.f, 0.f, 0.f};
  acc0 = __builtin_amdgcn_mfma_f32_16x16x32_bf16(a, b0, acc0, 0, 0, 0);
  acc1 = __builtin_amdgcn_mfma_f32_16x16x32_bf16(a, b1, acc1, 0, 0, 0);
  acc2 = __builtin_amdgcn_mfma_f32_16x16x32_bf16(a, b2, acc2, 0, 0, 0);
  acc3 = __builtin_amdgcn_mfma_f32_16x16x32_bf16(a, b3, acc3, 0, 0, 0);
  int ccol = lane & 15;
  int crow = (lane >> 4) * 4;
  float av0 = attn[ccol], av1 = attn[16 + ccol], av2 = attn[32 + ccol], av3 = attn[48 + ccol];
  float bv0 = fold[1024 + ccol], bv1 = fold[1024 + 16 + ccol];
  float bv2 = fold[1024 + 32 + ccol], bv3 = fold[1024 + 48 + ccol];
#pragma unroll
  for (int j = 0; j < 4; ++j) {
    int r = m0 + crow + j;
    int2 sd = sd_s[r];
    const ush* hsp = hs + (size_t)sd.x * 64;
    const ush* hdp = hd + (size_t)sd.y * 64;
    float f0 = acc0[j] + bf2f(hsp[ccol]) + bf2f(hdp[ccol]) + bv0;
    float f1 = acc1[j] + bf2f(hsp[16 + ccol]) + bf2f(hdp[16 + ccol]) + bv1;
    float f2 = acc2[j] + bf2f(hsp[32 + ccol]) + bf2f(hdp[32 + ccol]) + bv2;
    float f3 = acc3[j] + bf2f(hsp[48 + ccol]) + bf2f(hdp[48 + ccol]) + bv3;
    f0 = f0 >= 0.f ? f0 : 0.01f * f0;
    f1 = f1 >= 0.f ? f1 : 0.01f * f1;
    f2 = f2 >= 0.f ? f2 : 0.01f * f2;
    f3 = f3 >= 0.f ? f3 : 0.01f * f3;
    ush* fp = f116 + (size_t)r * 64;
    fp[ccol] = f2bf(f0);
    fp[16 + ccol] = f2bf(f1);
    fp[32 + ccol] = f2bf(f2);
    fp[48 + ccol] = f2bf(f3);
    float p = fmaf(f0, av0, fmaf(f1, av1, fmaf(f2, av2, f3 * av3)));
    p += __shfl_xor(p, 1, 64);
    p += __shfl_xor(p, 2, 64);
    p += __shfl_xor(p, 4, 64);
    p += __shfl_xor(p, 8, 64);
    if (ccol == 0) logit[r] = p;
  }
}

// ---------------- layer-2 hproj via MFMA: h1bf(NNx64) @ {ni,nj,node}(64x64) --------------
__global__ __launch_bounds__(256, 4) void mfma_hproj_kernel(
    const ush* __restrict__ h1bf, const ush* __restrict__ WfragH, ush* __restrict__ hs,
    ush* __restrict__ hd, ush* __restrict__ hn) {
  int wave = (blockIdx.x * blockDim.x + threadIdx.x) >> 6;
  int lane = threadIdx.x & 63;
  int m0 = wave * 16;
  if (m0 >= NN) return;
  int arow = lane & 15;
  int aoff = (lane >> 4) * 8;
  const ush* ap = h1bf + (size_t)(m0 + arow) * 64 + aoff;
  bf16x8 a0 = *(const bf16x8*)(ap);
  bf16x8 a1 = *(const bf16x8*)(ap + 32);
  const ush* wp = WfragH + lane * 8;
  int ccol = lane & 15;
  int crow = (lane >> 4) * 4;
#pragma unroll
  for (int m = 0; m < 3; ++m) {
    f32x4 acc0 = {0.f, 0.f, 0.f, 0.f};
    f32x4 acc1 = {0.f, 0.f, 0.f, 0.f};
    f32x4 acc2 = {0.f, 0.f, 0.f, 0.f};
    f32x4 acc3 = {0.f, 0.f, 0.f, 0.f};
    const ush* wm = wp + (size_t)m * 8 * 512;
    bf16x8 b0 = *(const bf16x8*)(wm + 0 * 512);
    bf16x8 b1 = *(const bf16x8*)(wm + 1 * 512);
    bf16x8 b2 = *(const bf16x8*)(wm + 2 * 512);
    bf16x8 b3 = *(const bf16x8*)(wm + 3 * 512);
    acc0 = __builtin_amdgcn_mfma_f32_16x16x32_bf16(a0, b0, acc0, 0, 0, 0);
    acc1 = __builtin_amdgcn_mfma_f32_16x16x32_bf16(a0, b1, acc1, 0, 0, 0);
    acc2 = __builtin_amdgcn_mfma_f32_16x16x32_bf16(a0, b2, acc2, 0, 0, 0);
    acc3 = __builtin_amdgcn_mfma_f32_16x16x32_bf16(a0, b3, acc3, 0, 0, 0);
    b0 = *(const bf16x8*)(wm + 4 * 512);
    b1 = *(const bf16x8*)(wm + 5 * 512);
    b2 = *(const bf16x8*)(wm + 6 * 512);
    b3 = *(const bf16x8*)(wm + 7 * 512);
    acc0 = __builtin_amdgcn_mfma_f32_16x16x32_bf16(a1, b0, acc0, 0, 0, 0);
    acc1 = __builtin_amdgcn_mfma_f32_16x16x32_bf16(a1, b1, acc1, 0, 0, 0);
    acc2 = __builtin_amdgcn_mfma_f32_16x16x32_bf16(a1, b2, acc2, 0, 0, 0);
    acc3 = __builtin_amdgcn_mfma_f32_16x16x32_bf16(a1, b3, acc3, 0, 0, 0);
    ush* outm = (m == 0) ? hs : (m == 1) ? hd : hn;
#pragma unroll
    for (int j = 0; j < 4; ++j) {
      ush* op = outm + (size_t)(m0 + crow + j) * 64;
      op[ccol] = f2bf(acc0[j]);
      op[16 + ccol] = f2bf(acc1[j]);
      op[32 + ccol] = f2bf(acc2[j]);
      op[48 + ccol] = f2bf(acc3[j]);
    }
  }
}

// ---------------- layer-2 edge GEMM via MFMA: f116(NEx64 bf16) @ fij(64x64) --------------
__global__ __launch_bounds__(256, 4) void mfma_fout_kernel(
    const ush* __restrict__ f116, const ush* __restrict__ Wfrag2, const float* __restrict__ bias,
    const ush* __restrict__ hs, const ush* __restrict__ hd, const int2* __restrict__ sd_s,
    const float* __restrict__ attn, float* __restrict__ logit) {
  int wave = (blockIdx.x * blockDim.x + threadIdx.x) >> 6;
  int lane = threadIdx.x & 63;
  int m0 = wave * 16;
  if (m0 >= NE) return;
  int arow = lane & 15;
  int aoff = (lane >> 4) * 8;
  const ush* ap = f116 + (size_t)(m0 + arow) * 64 + aoff;
  const ush* wp = Wfrag2 + lane * 8;
  f32x4 acc0 = {0.f, 0.f, 0.f, 0.f};
  f32x4 acc1 = {0.f, 0.f, 0.f, 0.f};
  f32x4 acc2 = {0.f, 0.f, 0.f, 0.f};
  f32x4 acc3 = {0.f, 0.f, 0.f, 0.f};
#pragma unroll
  for (int kk = 0; kk < 2; ++kk) {
    bf16x8 a = *(const bf16x8*)(ap + kk * 32);
    bf16x8 b0 = *(const bf16x8*)(wp + (size_t)(kk * 4 + 0) * 512);
    bf16x8 b1 = *(const bf16x8*)(wp + (size_t)(kk * 4 + 1) * 512);
    bf16x8 b2 = *(const bf16x8*)(wp + (size_t)(kk * 4 + 2) * 512);
    bf16x8 b3 = *(const bf16x8*)(wp + (size_t)(kk * 4 + 3) * 512);
    acc0 = __builtin_amdgcn_mfma_f32_16x16x32_bf16(a, b0, acc0, 0, 0, 0);
    acc1 = __builtin_amdgcn_mfma_f32_16x16x32_bf16(a, b1, acc1, 0, 0, 0);
    acc2 = __builtin_amdgcn_mfma_f32_16x16x32_bf16(a, b2, acc2, 0, 0, 0);
    acc3 = __builtin_amdgcn_mfma_f32_16x16x32_bf16(a, b3, acc3, 0, 0, 0);
  }
  int ccol = lane & 15;
  int crow = (lane >> 4) * 4;
  float av0 = attn[ccol], av1 = attn[16 + ccol], av2 = attn[32 + ccol], av3 = attn[48 + ccol];
  float bv0 = bias[ccol], bv1 = bias[16 + ccol], bv2 = bias[32 + ccol], bv3 = bias[48 + ccol];
#pragma unroll
  for (int j = 0; j < 4; ++j) {
    int r = m0 + crow + j;
    int2 sd = sd_s[r];
    const ush* hsp = hs + (size_t)sd.x * 64;
    const ush* hdp = hd + (size_t)sd.y * 64;
    float f0 = acc0[j] + bf2f(hsp[ccol]) + bf2f(hdp[ccol]) + bv0;
    float f1 = acc1[j] + bf2f(hsp[16 + ccol]) + bf2f(hdp[16 + ccol]) + bv1;
    float f2 = acc2[j] + bf2f(hsp[32 + ccol]) + bf2f(hdp[32 + ccol]) + bv2;
    float f3 = acc3[j] + bf2f(hsp[48 + ccol]) + bf2f(hdp[48 + ccol]) + bv3;
    f0 = f0 >= 0.f ? f0 : 0.01f * f0;
    f1 = f1 >= 0.f ? f1 : 0.01f * f1;
    f2 = f2 >= 0.f ? f2 : 0.01f * f2;
    f3 = f3 >= 0.f ? f3 : 0.01f * f3;
    float p = fmaf(f0, av0, fmaf(f1, av1, fmaf(f2, av2, f3 * av3)));
    p += __shfl_xor(p, 1, 64);
    p += __shfl_xor(p, 2, 64);
    p += __shfl_xor(p, 4, 64);
    p += __shfl_xor(p, 8, 64);
    if (ccol == 0) logit[r] = p;
  }
}

// ---------------- EGAT: gather-aggregate; OSTRIDE lets layer-2 write out[] directly ------
template <bool BF16OUT, int OSTRIDE>
__global__ __launch_bounds__(256, 4) void agg_gather_kernel(
    const ush* __restrict__ hn, const float* __restrict__ logit, const int* __restrict__ rowptr,
    const int* __restrict__ deg, const int2* __restrict__ sd_s, void* __restrict__ hnew) {
  int wave = (blockIdx.x * blockDim.x + threadIdx.x) >> 6;
  int lane = threadIdx.x & 63;
  if (wave >= NN) return;
  int n = wave, d = deg[n], r0 = rowptr[n];
  if (d == 0) {
    if (BF16OUT) ((ush*)hnew)[(size_t)n * OSTRIDE + lane] = 0;
    else ((float*)hnew)[(size_t)n * OSTRIDE + lane] = 0.f;
    return;
  }
  float sum = 0.f, acc0 = 0.f, acc1 = 0.f, acc2 = 0.f, acc3 = 0.f;
  int j = 0;
  for (; j + 3 < d; j += 4) {
    int jj = r0 + j;
    int s0 = sd_s[jj + 0].x, s1 = sd_s[jj + 1].x, s2 = sd_s[jj + 2].x, s3 = sd_s[jj + 3].x;
    float l0 = logit[jj + 0], l1 = logit[jj + 1], l2 = logit[jj + 2], l3 = logit[jj + 3];
    ush h0 = hn[(size_t)s0 * 64 + lane];
    ush h1 = hn[(size_t)s1 * 64 + lane];
    ush h2 = hn[(size_t)s2 * 64 + lane];
    ush h3 = hn[(size_t)s3 * 64 + lane];
    float w0 = __expf(l0), w1 = __expf(l1);
    float w2 = __expf(l2), w3 = __expf(l3);
    sum += (w0 + w1) + (w2 + w3);
    acc0 = fmaf(w0, bf2f(h0), acc0);
    acc1 = fmaf(w1, bf2f(h1), acc1);
    acc2 = fmaf(w2, bf2f(h2), acc2);
    acc3 = fmaf(w3, bf2f(h3), acc3);
  }
  for (; j < d; ++j) {
    int jj = r0 + j;
    float w = __expf(logit[jj]);
    sum += w;
    acc0 = fmaf(w, bf2f(hn[(size_t)sd_s[jj].x * 64 + lane]), acc0);
  }
  float r = ((acc0 + acc1) + (acc2 + acc3)) / sum;
  if (BF16OUT) ((ush*)hnew)[(size_t)n * OSTRIDE + lane] = f2bf(r);
  else ((float*)hnew)[(size_t)n * OSTRIDE + lane] = r;
}

// ---------------- NNConv fused: gather G into LDS, MFMA GEMM from LDS -------------------
__global__ __launch_bounds__(256, 4) void nnconv_fused_kernel(
    const ush* __restrict__ face16, const ush* __restrict__ ef16,
    const int* __restrict__ rowptr, const int* __restrict__ deg,
    const int2* __restrict__ sd_s, const ush* __restrict__ Wfrag,
    float* __restrict__ sArr) {
  __shared__ ush Gs[16][552];
  int wid = threadIdx.x >> 6;
  int lane = threadIdx.x & 63;
  int nbase = blockIdx.x * 16;  // NN % 16 == 0
  int k4 = lane >> 2, ib = lane & 3;
  for (int q = 0; q < 4; ++q) {
    int row = wid * 4 + q;
    int n = nbase + row;
    int d = deg[n], r0 = rowptr[n];
    float g[8], fs[8];
#pragma unroll
    for (int u = 0; u < 8; ++u) { g[u] = 0.f; fs[u] = 0.f; }
    int j = 0;
    for (; j + 1 < d; j += 2) {
      int jj = r0 + j;
      int s0 = sd_s[jj].x, s1 = sd_s[jj + 1].x;
      float ev0 = bf2f(ef16[(size_t)jj * 16 + k4]);
      float ev1 = bf2f(ef16[(size_t)(jj + 1) * 16 + k4]);
      uint4 u0 = *(const uint4*)(face16 + (size_t)s0 * 32 + ib * 8);
      uint4 u1 = *(const uint4*)(face16 + (size_t)s1 * 32 + ib * 8);
      float fa0[8], fa1[8];
      unp8(u0, fa0);
      unp8(u1, fa1);
#pragma unroll
      for (int u = 0; u < 8; ++u) {
        g[u] = fmaf(ev0, fa0[u], g[u]);
        g[u] = fmaf(ev1, fa1[u], g[u]);
      }
      if (k4 == 0) {
#pragma unroll
        for (int u = 0; u < 8; ++u) fs[u] += fa0[u] + fa1[u];
      }
    }
    if (j < d) {
      int jj = r0 + j;
      float ev0 = bf2f(ef16[(size_t)jj * 16 + k4]);
      uint4 u0 = *(const uint4*)(face16 + (size_t)sd_s[jj].x * 32 + ib * 8);
      float fa0[8];
      unp8(u0, fa0);
#pragma unroll
      for (int u = 0; u < 8; ++u) g[u] = fmaf(ev0, fa0[u], g[u]);
      if (k4 == 0) {
#pragma unroll
        for (int u = 0; u < 8; ++u) fs[u] += fa0[u];
      }
    }
    uint4 pv;
    pv.x = pack2(g[0], g[1]); pv.y = pack2(g[2], g[3]);
    pv.z = pack2(g[4], g[5]); pv.w = pack2(g[6], g[7]);
    *(uint4*)&Gs[row][lane * 8] = pv;
    if (k4 == 0) {
      uint4 fv;
      fv.x = pack2(fs[0], fs[1]); fv.y = pack2(fs[2], fs[3]);
      fv.z = pack2(fs[4], fs[5]); fv.w = pack2(fs[6], fs[7]);
      *(uint4*)&Gs[row][512 + ib * 8] = fv;
    }
  }
  __syncthreads();
  if (wid < 2) {
    int arow = lane & 15;
    int aoff = (lane >> 4) * 8;
    const ush* wp = Wfrag + lane * 8;
    f32x4 acc = {0.f, 0.f, 0.f, 0.f};
#pragma unroll 4
    for (int kk = 0; kk < 17; ++kk) {
      bf16x8 a = *(const bf16x8*)&Gs[arow][kk * 32 + aoff];
      bf16x8 b = *(const bf16x8*)(wp + (size_t)(kk * 2 + wid) * 512);
      acc = __builtin_amdgcn_mfma_f32_16x16x32_bf16(a, b, acc, 0, 0, 0);
    }
    int ccol = lane & 15;
    int crow = (lane >> 4) * 4;
#pragma unroll
    for (int j = 0; j < 4; ++j) {
      int r = nbase + crow + j;
      sArr[(size_t)r * 32 + wid * 16 + ccol] = acc[j];
    }
  }
}

// ---------------- combine node_features + gate logit + fused block max -------------------
__global__ void combine_gate_kernel(const float* __restrict__ sArr,
                                    const int* __restrict__ deg, const float* __restrict__ nn_bias,
                                    const float* __restrict__ gate_w, const float* __restrict__ gate_b,
                                    float* __restrict__ out, float* __restrict__ g,
                                    unsigned* __restrict__ gmax) {
  int wave = (blockIdx.x * blockDim.x + threadIdx.x) >> 6;
  int lane = threadIdx.x & 63;
  float pf = -3.0e38f;
  if (wave < NN) {
    int n = wave;
    float v0 = out[(size_t)n * 128 + lane];
    int c1 = lane + 64;
    float v1 = (c1 < 96)
                   ? sArr[(size_t)n * 32 + (c1 - 64)] / fmaxf((float)deg[n], 1.0f) + nn_bias[c1 - 64]
                   : 0.f;
    out[(size_t)n * 128 + c1] = v1;
    float p = v0 * gate_w[lane] + ((c1 < 96) ? v1 * gate_w[c1] : 0.f);
#pragma unroll
    for (int off = 32; off; off >>= 1) p += __shfl_xor(p, off, 64);
    p += gate_b[0];
    if (lane == 0) g[n] = p;
    pf = p;
  }
  __shared__ float sm[4];
  if (lane == 0) sm[threadIdx.x >> 6] = pf;
  __syncthreads();
  if (threadIdx.x == 0) {
    float m = fmaxf(fmaxf(sm[0], sm[1]), fmaxf(sm[2], sm[3]));
    atomicMax(gmax, ord_enc(m));
  }
}

// ---------------- pooling: exp + weighted accumulate into per-row-stream partials --------
__global__ __launch_bounds__(256, 4) void pool_exp_kernel(
    const float* __restrict__ nf, const float* __restrict__ g, const unsigned* __restrict__ gmax,
    float* __restrict__ pacc, float* __restrict__ wsb) {
  int o = threadIdx.x & 127;
  int half = threadIdx.x >> 7;
  int ri = blockIdx.x * 2 + half;   // 0 .. 2*PB-1
  float m = ord_dec(*gmax);
  float acc0 = 0.f, acc1 = 0.f, ws = 0.f;
  int n = ri;
  const int STR = PB * 2;
  for (; n + STR < NN; n += STR * 2) {
    float w0 = __expf(g[n] - m);
    float w1 = __expf(g[n + STR] - m);
    float v0 = nf[(size_t)n * 128 + o];
    float v1 = nf[(size_t)(n + STR) * 128 + o];
    ws += w0 + w1;
    acc0 = fmaf(w0, v0, acc0);
    acc1 = fmaf(w1, v1, acc1);
  }
  if (n < NN) {
    float w = __expf(g[n] - m);
    ws += w;
    acc0 = fmaf(w, nf[(size_t)n * 128 + o], acc0);
  }
  pacc[(size_t)ri * 128 + o] = acc0 + acc1;
  if (o == 0) wsb[ri] = ws;
}

__global__ void pool_reduce_kernel(const float* __restrict__ pacc, const float* __restrict__ wsb,
                                   float* __restrict__ gacc, float* __restrict__ gsum) {
  int b = blockIdx.x;
  int t = threadIdx.x;  // 256
  float v = 0.f;
  if (b < 128) {
    for (int ri = t; ri < PB * 2; ri += 256) v += pacc[(size_t)ri * 128 + b];
  } else {
    for (int ri = t; ri < PB * 2; ri += 256) v += wsb[ri];
  }
#pragma unroll
  for (int off = 32; off; off >>= 1) v += __shfl_xor(v, off, 64);
  __shared__ float sm[4];
  int lane = t & 63, wid = t >> 6;
  if (lane == 0) sm[wid] = v;
  __syncthreads();
  if (t == 0) {
    float s = (sm[0] + sm[1]) + (sm[2] + sm[3]);
    if (b < 128) gacc[b] = s;
    else gsum[0] = s;
  }
}

__global__ void finalize_kernel(const float* __restrict__ gacc, const float* __restrict__ gsum,
                                float* __restrict__ out) {
  int o = threadIdx.x;
  if (o < 128) out[(size_t)NN * 128 + o] = gacc[o] / gsum[0];
}

extern "C" void kernel_launch(void* const* d_in, const int* in_sizes, int n_in,
                              void* d_out, int out_size, void* d_ws, size_t ws_size,
                              hipStream_t stream) {
  const float* face    = (const float*)d_in[0];
  const float* ef      = (const float*)d_in[1];
  const float* fp_w    = (const float*)d_in[2];
  const float* fp_b    = (const float*)d_in[3];
  const float* ep_w    = (const float*)d_in[4];
  const float* ep_b    = (const float*)d_in[5];
  const float* nn_w    = (const float*)d_in[6];
  const float* nn_b    = (const float*)d_in[7];
  const float* nn_bias = (const float*)d_in[8];
  const float* gate_w  = (const float*)d_in[9];
  const float* gate_b  = (const float*)d_in[10];
  const int*   src     = (const int*)d_in[11];
  const int*   dst     = (const int*)d_in[12];
  const float* e1_attn = (const float*)d_in[17];
  const float* e2_ni   = (const float*)d_in[19];
  const float* e2_nj   = (const float*)d_in[20];
  const float* e2_fij  = (const float*)d_in[21];
  const float* e2_attn = (const float*)d_in[23];
  const float* e2_bias = (const float*)d_in[24];
  float* out = (float*)d_out;

  char* p = (char*)d_ws;
  auto alloc = [&](size_t nfloats) {
    float* r = (float*)p;
    p += ((nfloats * 4 + 255) / 256) * 256;
    return r;
  };
  ush* h1bf = (ush*)alloc((size_t)NN * 32);   // layer-1 output (bf16)
  ush* hs16 = (ush*)alloc((size_t)NN * 32);   // NN*64 bf16
  ush* hd16 = (ush*)alloc((size_t)NN * 32);
  ush* hn16 = (ush*)alloc((size_t)NN * 32);
  ush* f116 = (ush*)alloc((size_t)NE * 32);   // NE*64 bf16 (dst-sorted order)
  float* logit = alloc(NE);                   // dst-sorted order
  float* sArr  = alloc((size_t)NN * 32);
  float* g     = alloc(NN);
  float* gacc  = alloc(128);
  float* gsum  = alloc(1);
  unsigned* gmax = (unsigned*)alloc(1);
  float* fold  = alloc(7424);
  ush* Wfrag   = (ush*)alloc(17408 / 2);      // nn MFMA B-fragments
  ush* Wfrag2  = (ush*)alloc(4096 / 2);       // e2_fij MFMA B-fragments
  ush* WfragH  = (ush*)alloc(12288 / 2);      // e2_{ni,nj,node} MFMA B-fragments
  ush* Wf1frag = (ush*)alloc(2048 / 2);       // layer-1 folded fij MFMA B-fragments
  ush* WfragH1 = (ush*)alloc(6144 / 2);       // layer-1 folded {ni,nj,node} B-fragments
  ush* face16  = (ush*)alloc((size_t)NN * 16);  // NN*32 bf16
  ush* ef16    = (ush*)alloc((size_t)NE * 8);   // NE*16 bf16 (dst-sorted, no padding)
  float* pacc  = alloc((size_t)PB * 2 * 128); // pooling partials
  float* wsb   = alloc(PB * 2);
  // dst-CSR
  int* deg    = (int*)alloc(NN);
  int* rowptr = (int*)alloc(NN);
  int* cursor = (int*)alloc(NN);
  int* partial = (int*)alloc(256);
  int2* sd_s  = (int2*)alloc((size_t)NE * 2);  // packed (src,dst), dst-sorted

  const int B = 256;
  const int NB256 = cdiv(NN, 256);

  // ---- CSR build (dst-sorted) + fused edge permutation (bf16 only) ----
  hipMemsetAsync(deg, 0, NN * 4, stream);
  deg_kernel<<<cdiv(NE, B), B, 0, stream>>>(dst, deg);
  scan1_kernel<<<NB256, 256, 0, stream>>>(deg, rowptr, partial);
  scan2_kernel<<<1, 256, 0, stream>>>(partial, NB256);
  scan3_kernel<<<NB256, 256, 0, stream>>>(rowptr, partial, cursor);
  scatter_dst_kernel<<<cdiv(NE, B), B, 0, stream>>>(src, dst, ef, cursor, sd_s, ef16);

  // ---- weight prep: fold, then merged fragment packs + face convert ----
  fold_kernel<<<29, B, 0, stream>>>(fp_w, fp_b, ep_w, ep_b,
                                    (const float*)d_in[15], (const float*)d_in[18],
                                    (const float*)d_in[13], (const float*)d_in[14],
                                    (const float*)d_in[16], fold);
  prep_rest_kernel<<<cdiv(41984 + NN * 8, B), B, 0, stream>>>(
      fold, nn_w, nn_b, e2_fij, e2_ni, e2_nj, (const float*)d_in[22], face,
      Wf1frag, WfragH1, Wfrag, Wfrag2, WfragH, face16);

  // ---- EGAT layer 1 (all matmuls on matrix cores) ----
  mfma_hproj1_kernel<<<cdiv(NN * 4, B), B, 0, stream>>>(face16, WfragH1, fold, hs16, hd16, hn16);
  mfma_fout1_kernel<<<cdiv(NE * 4, B), B, 0, stream>>>(ef16, Wf1frag, fold, hs16, hd16,
                                                       sd_s, e1_attn, f116, logit);
  agg_gather_kernel<true, 64><<<cdiv(NN * 64, B), B, 0, stream>>>(hn16, logit, rowptr, deg,
                                                                  sd_s, h1bf);

  // ---- EGAT layer 2 (hproj + edge GEMM on matrix cores) ----
  mfma_hproj_kernel<<<cdiv(NN * 4, B), B, 0, stream>>>(h1bf, WfragH, hs16, hd16, hn16);
  mfma_fout_kernel<<<cdiv(NE * 4, B), B, 0, stream>>>(f116, Wfrag2, e2_bias, hs16, hd16,
                                                      sd_s, e2_attn, logit);
  // layer-2 aggregate writes Gf directly into out[:, 0:64]
  agg_gather_kernel<false, 128><<<cdiv(NN * 64, B), B, 0, stream>>>(hn16, logit, rowptr, deg,
                                                                    sd_s, out);

  // ---- NNConv fused (G lives only in LDS; face gathered as bf16) ----
  nnconv_fused_kernel<<<NN / 16, B, 0, stream>>>(face16, ef16, rowptr, deg, sd_s, Wfrag, sArr);

  // ---- combine node features + gate logits + fused max ----
  hipMemsetAsync(gmax, 0, 4, stream);
  combine_gate_kernel<<<cdiv(NN * 64, B), B, 0, stream>>>(sArr, deg, nn_bias, gate_w,
                                                          gate_b, out, g, gmax);
  pool_exp_kernel<<<PB, B, 0, stream>>>(out, g, gmax, pacc, wsb);
  pool_reduce_kernel<<<129, B, 0, stream>>>(pacc, wsb, gacc, gsum);
  finalize_kernel<<<1, 128, 0, stream>>>(gacc, gsum, out);
}

// Round 29
// 231.133 us; speedup vs baseline: 1.6956x; 1.6956x over previous
//
#include <hip/hip_runtime.h>

#define NN 60000
#define NE 300000
#define PB 768
typedef unsigned short ush;
typedef __attribute__((ext_vector_type(8))) short bf16x8;
typedef __attribute__((ext_vector_type(4))) float f32x4;

static inline int cdiv(int a, int b) { return (a + b - 1) / b; }

__device__ inline unsigned ord_enc(float x) {
  unsigned u = __float_as_uint(x);
  return (u & 0x80000000u) ? ~u : (u | 0x80000000u);
}
__device__ inline float ord_dec(unsigned u) {
  return __uint_as_float((u & 0x80000000u) ? (u & 0x7fffffffu) : ~u);
}
__device__ inline float bf2f(unsigned u16) { return __uint_as_float(u16 << 16); }
__device__ inline ush f2bf(float x) {
  unsigned u = __float_as_uint(x);
  return (ush)((u + 0x7FFFu + ((u >> 16) & 1u)) >> 16);
}
__device__ inline unsigned pack2(float lo, float hi) {
  return ((unsigned)f2bf(hi) << 16) | (unsigned)f2bf(lo);
}
__device__ inline void unp8(uint4 u, float* f) {
  f[0] = bf2f(u.x & 0xffff); f[1] = bf2f(u.x >> 16);
  f[2] = bf2f(u.y & 0xffff); f[3] = bf2f(u.y >> 16);
  f[4] = bf2f(u.z & 0xffff); f[5] = bf2f(u.z >> 16);
  f[6] = bf2f(u.w & 0xffff); f[7] = bf2f(u.w >> 16);
}

// ================= CSR build (dst-sorted) =================
__global__ void deg_kernel(const int* __restrict__ key, int* __restrict__ deg) {
  int e = blockIdx.x * blockDim.x + threadIdx.x;
  if (e < NE) atomicAdd(deg + key[e], 1);
}

__global__ void scan1_kernel(const int* __restrict__ deg, int* __restrict__ rowptr,
                             int* __restrict__ partial) {
  __shared__ int s[256];
  int i = blockIdx.x * 256 + threadIdx.x;
  int v = (i < NN) ? deg[i] : 0;
  s[threadIdx.x] = v;
  __syncthreads();
  for (int off = 1; off < 256; off <<= 1) {
    int t = (threadIdx.x >= off) ? s[threadIdx.x - off] : 0;
    __syncthreads();
    s[threadIdx.x] += t;
    __syncthreads();
  }
  if (i < NN) rowptr[i] = s[threadIdx.x] - v;
  if (threadIdx.x == 255) partial[blockIdx.x] = s[255];
}

__global__ void scan2_kernel(int* __restrict__ partial, int nb) {
  __shared__ int s[256];
  int v = (threadIdx.x < nb) ? partial[threadIdx.x] : 0;
  s[threadIdx.x] = v;
  __syncthreads();
  for (int off = 1; off < 256; off <<= 1) {
    int t = (threadIdx.x >= off) ? s[threadIdx.x - off] : 0;
    __syncthreads();
    s[threadIdx.x] += t;
    __syncthreads();
  }
  if (threadIdx.x < nb) partial[threadIdx.x] = s[threadIdx.x] - v;
}

__global__ void scan3_kernel(int* __restrict__ rowptr, const int* __restrict__ partial,
                             int* __restrict__ cursor) {
  int i = blockIdx.x * 256 + threadIdx.x;
  if (i < NN) {
    int r = rowptr[i] + partial[blockIdx.x];
    rowptr[i] = r;
    cursor[i] = r;
  }
}

// scatter + ef permutation fused; emits ef16 (NEx16 bf16) + packed (src,dst) int2
__global__ void scatter_dst_kernel(const int* __restrict__ src, const int* __restrict__ dst,
                                   const float* __restrict__ ef, int* __restrict__ cursor,
                                   int2* __restrict__ sd_s, ush* __restrict__ ef16) {
  int e = blockIdx.x * blockDim.x + threadIdx.x;
  if (e >= NE) return;
  int d = dst[e];
  int j = atomicAdd(cursor + d, 1);
  sd_s[j] = make_int2(src[e], d);
  const float4* ep = (const float4*)(ef + (size_t)e * 16);
  float4 a = ep[0], b = ep[1], c = ep[2], dd = ep[3];
  uint4* bp = (uint4*)(ef16 + (size_t)j * 16);
  uint4 p0, p1;
  p0.x = pack2(a.x, a.y); p0.y = pack2(a.z, a.w);
  p0.z = pack2(b.x, b.y); p0.w = pack2(b.z, b.w);
  p1.x = pack2(c.x, c.y); p1.y = pack2(c.z, c.w);
  p1.z = pack2(dd.x, dd.y); p1.w = pack2(dd.z, dd.w);
  bp[0] = p0; bp[1] = p1;
}

// ---------------- fold: precompute folded weight products (7424 dots of length 64) -------
__global__ void fold_kernel(const float* __restrict__ fp_w, const float* __restrict__ fp_b,
                            const float* __restrict__ ep_w, const float* __restrict__ ep_b,
                            const float* __restrict__ fij, const float* __restrict__ ebias,
                            const float* __restrict__ ni, const float* __restrict__ nj,
                            const float* __restrict__ node, float* __restrict__ fold) {
  int t = blockIdx.x * blockDim.x + threadIdx.x;
  if (t >= 7424) return;
  int o = t & 63;
  const float* A;
  const float* B;
  float init = 0.f;
  if (t < 1024)      { A = ep_w + (size_t)(t >> 6) * 64; B = fij + o; }
  else if (t < 1088) { A = ep_b; B = fij + o; init = ebias[o]; }
  else if (t < 3136) { A = fp_w + (size_t)((t - 1088) >> 6) * 64; B = ni + o; }
  else if (t < 5184) { A = fp_w + (size_t)((t - 3136) >> 6) * 64; B = nj + o; }
  else if (t < 7232) { A = fp_w + (size_t)((t - 5184) >> 6) * 64; B = node + o; }
  else if (t < 7296) { A = fp_b; B = ni + o; }
  else if (t < 7360) { A = fp_b; B = nj + o; }
  else               { A = fp_b; B = node + o; }
  float a = init;
  for (int i = 0; i < 64; ++i) a = fmaf(A[i], B[(size_t)i * 64], a);
  fold[t] = a;
}

// ---------------- merged prep: fold1_frag | nnwt | fij | hproj_frag | face16 -------------
__global__ void prep_rest_kernel(const float* __restrict__ fold, const float* __restrict__ nn_w,
                                 const float* __restrict__ nn_b, const float* __restrict__ fij,
                                 const float* __restrict__ ni, const float* __restrict__ nj,
                                 const float* __restrict__ node, const float* __restrict__ face,
                                 ush* __restrict__ Wf1frag, ush* __restrict__ WfragH1,
                                 ush* __restrict__ Wfrag, ush* __restrict__ Wfrag2,
                                 ush* __restrict__ WfragH, ush* __restrict__ face16) {
  int t = blockIdx.x * blockDim.x + threadIdx.x;
  if (t < 8192) {
    if (t < 2048) {
      int i = t & 7, lane = (t >> 3) & 63, ct = t >> 9;
      int k = (lane >> 4) * 8 + i;
      int o = ct * 16 + (lane & 15);
      Wf1frag[t] = (k < 16) ? f2bf(fold[(size_t)k * 64 + o]) : 0;
    } else {
      int idx = t - 2048;
      int i = idx & 7, lane = (idx >> 3) & 63, ct = (idx >> 9) & 3, m = idx >> 11;
      int k = (lane >> 4) * 8 + i;
      int o = ct * 16 + (lane & 15);
      WfragH1[idx] = f2bf(fold[1088 + (size_t)m * 2048 + (size_t)k * 64 + o]);
    }
  } else if (t < 25600) {
    int u = t - 8192;
    int i = u & 7, lane = (u >> 3) & 63, ct = (u >> 9) & 1, kk = u >> 10;
    int k = kk * 32 + (lane >> 4) * 8 + i;
    int o = ct * 16 + (lane & 15);
    float v = (k < 512) ? nn_w[(size_t)(k >> 5) * 1024 + (k & 31) * 32 + o]
                        : nn_b[(k - 512) * 32 + o];
    Wfrag[u] = f2bf(v);
  } else if (t < 29696) {
    int u = t - 25600;
    int i = u & 7, lane = (u >> 3) & 63, ct = (u >> 9) & 3, kk = u >> 11;
    int k = kk * 32 + (lane >> 4) * 8 + i;
    int o = ct * 16 + (lane & 15);
    Wfrag2[u] = f2bf(fij[(size_t)k * 64 + o]);
  } else if (t < 41984) {
    int u = t - 29696;
    int i = u & 7, lane = (u >> 3) & 63, ct = (u >> 9) & 3, kk = (u >> 11) & 1, m = u >> 12;
    int k = kk * 32 + (lane >> 4) * 8 + i;
    int o = ct * 16 + (lane & 15);
    const float* W = (m == 0) ? ni : (m == 1) ? nj : node;
    WfragH[u] = f2bf(W[(size_t)k * 64 + o]);
  } else if (t < 41984 + NN * 8) {
    int u = t - 41984;
    const float4 v = ((const float4*)face)[u];
    ((uint2*)face16)[u] = make_uint2(pack2(v.x, v.y), pack2(v.z, v.w));
  }
}

// ---------------- layer-1 hproj via MFMA: face16(NNx32) @ folded {ni,nj,node}(32x64) -----
__global__ __launch_bounds__(256, 4) void mfma_hproj1_kernel(
    const ush* __restrict__ face16, const ush* __restrict__ WfragH1,
    const float* __restrict__ fold, ush* __restrict__ hs, ush* __restrict__ hd,
    ush* __restrict__ hn) {
  int wave = (blockIdx.x * blockDim.x + threadIdx.x) >> 6;
  int lane = threadIdx.x & 63;
  int m0 = wave * 16;
  if (m0 >= NN) return;
  int arow = lane & 15;
  int aoff = (lane >> 4) * 8;
  bf16x8 a = *(const bf16x8*)(face16 + (size_t)(m0 + arow) * 32 + aoff);
  int ccol = lane & 15;
  int crow = (lane >> 4) * 4;
#pragma unroll
  for (int m = 0; m < 3; ++m) {
    const ush* wm = WfragH1 + (size_t)m * 2048 + lane * 8;
    bf16x8 b0 = *(const bf16x8*)(wm + 0 * 512);
    bf16x8 b1 = *(const bf16x8*)(wm + 1 * 512);
    bf16x8 b2 = *(const bf16x8*)(wm + 2 * 512);
    bf16x8 b3 = *(const bf16x8*)(wm + 3 * 512);
    f32x4 acc0 = {0.f, 0.f, 0.f, 0.f};
    f32x4 acc1 = {0.f, 0.f, 0.f, 0.f};
    f32x4 acc2 = {0.f, 0.f, 0.f, 0.f};
    f32x4 acc3 = {0.f, 0.f, 0.f, 0.f};
    acc0 = __builtin_amdgcn_mfma_f32_16x16x32_bf16(a, b0, acc0, 0, 0, 0);
    acc1 = __builtin_amdgcn_mfma_f32_16x16x32_bf16(a, b1, acc1, 0, 0, 0);
    acc2 = __builtin_amdgcn_mfma_f32_16x16x32_bf16(a, b2, acc2, 0, 0, 0);
    acc3 = __builtin_amdgcn_mfma_f32_16x16x32_bf16(a, b3, acc3, 0, 0, 0);
    float bv0 = fold[7232 + m * 64 + ccol];
    float bv1 = fold[7232 + m * 64 + 16 + ccol];
    float bv2 = fold[7232 + m * 64 + 32 + ccol];
    float bv3 = fold[7232 + m * 64 + 48 + ccol];
    ush* outm = (m == 0) ? hs : (m == 1) ? hd : hn;
#pragma unroll
    for (int j = 0; j < 4; ++j) {
      ush* op = outm + (size_t)(m0 + crow + j) * 64;
      op[ccol] = f2bf(acc0[j] + bv0);
      op[16 + ccol] = f2bf(acc1[j] + bv1);
      op[32 + ccol] = f2bf(acc2[j] + bv2);
      op[48 + ccol] = f2bf(acc3[j] + bv3);
    }
  }
}

// ---------------- layer-1 edge GEMM via MFMA: ef16(NEx16) @ Wf1(32x64, folded, k>=16 = 0) -
__global__ __launch_bounds__(256, 4) void mfma_fout1_kernel(
    const ush* __restrict__ ef16, const ush* __restrict__ Wf1frag, const float* __restrict__ fold,
    const ush* __restrict__ hs, const ush* __restrict__ hd, const int2* __restrict__ sd_s,
    const float* __restrict__ attn, ush* __restrict__ f116, float* __restrict__ logit) {
  int wave = (blockIdx.x * blockDim.x + threadIdx.x) >> 6;
  int lane = threadIdx.x & 63;
  int m0 = wave * 16;
  if (m0 >= NE) return;
  int arow = lane & 15;
  int aoff = (lane >> 4) * 8;
  bf16x8 a = {0, 0, 0, 0, 0, 0, 0, 0};
  if (aoff < 16) a = *(const bf16x8*)(ef16 + (size_t)(m0 + arow) * 16 + aoff);
  const ush* wp = Wf1frag + lane * 8;
  bf16x8 b0 = *(const bf16x8*)(wp + 0 * 512);
  bf16x8 b1 = *(const bf16x8*)(wp + 1 * 512);
  bf16x8 b2 = *(const bf16x8*)(wp + 2 * 512);
  bf16x8 b3 = *(const bf16x8*)(wp + 3 * 512);
  f32x4 acc0 = {0.f, 0.f, 0.f, 0.f};
  f32x4 acc1 = {0.f, 0.f, 0.f, 0.f};
  f32x4 acc2 = {0.f, 0.f, 0.f, 0.f};
  f32x4 acc3 = {0.f, 0.f, 0.f, 0.f};
  acc0 = __builtin_amdgcn_mfma_f32_16x16x32_bf16(a, b0, acc0, 0, 0, 0);
  acc1 = __builtin_amdgcn_mfma_f32_16x16x32_bf16(a, b1, acc1, 0, 0, 0);
  acc2 = __builtin_amdgcn_mfma_f32_16x16x32_bf16(a, b2, acc2, 0, 0, 0);
  acc3 = __builtin_amdgcn_mfma_f32_16x16x32_bf16(a, b3, acc3, 0, 0, 0);
  int ccol = lane & 15;
  int crow = (lane >> 4) * 4;
  float av0 = attn[ccol], av1 = attn[16 + ccol], av2 = attn[32 + ccol], av3 = attn[48 + ccol];
  float bv0 = fold[1024 + ccol], bv1 = fold[1024 + 16 + ccol];
  float bv2 = fold[1024 + 32 + ccol], bv3 = fold[1024 + 48 + ccol];
#pragma unroll
  for (int j = 0; j < 4; ++j) {
    int r = m0 + crow + j;
    int2 sd = sd_s[r];
    const ush* hsp = hs + (size_t)sd.x * 64;
    const ush* hdp = hd + (size_t)sd.y * 64;
    float f0 = acc0[j] + bf2f(hsp[ccol]) + bf2f(hdp[ccol]) + bv0;
    float f1 = acc1[j] + bf2f(hsp[16 + ccol]) + bf2f(hdp[16 + ccol]) + bv1;
    float f2 = acc2[j] + bf2f(hsp[32 + ccol]) + bf2f(hdp[32 + ccol]) + bv2;
    float f3 = acc3[j] + bf2f(hsp[48 + ccol]) + bf2f(hdp[48 + ccol]) + bv3;
    f0 = f0 >= 0.f ? f0 : 0.01f * f0;
    f1 = f1 >= 0.f ? f1 : 0.01f * f1;
    f2 = f2 >= 0.f ? f2 : 0.01f * f2;
    f3 = f3 >= 0.f ? f3 : 0.01f * f3;
    ush* fp = f116 + (size_t)r * 64;
    fp[ccol] = f2bf(f0);
    fp[16 + ccol] = f2bf(f1);
    fp[32 + ccol] = f2bf(f2);
    fp[48 + ccol] = f2bf(f3);
    float p = fmaf(f0, av0, fmaf(f1, av1, fmaf(f2, av2, f3 * av3)));
    p += __shfl_xor(p, 1, 64);
    p += __shfl_xor(p, 2, 64);
    p += __shfl_xor(p, 4, 64);
    p += __shfl_xor(p, 8, 64);
    if (ccol == 0) logit[r] = p;
  }
}

// ---------------- layer-2 hproj via MFMA: h1bf(NNx64) @ {ni,nj,node}(64x64) --------------
__global__ __launch_bounds__(256, 4) void mfma_hproj_kernel(
    const ush* __restrict__ h1bf, const ush* __restrict__ WfragH, ush* __restrict__ hs,
    ush* __restrict__ hd, ush* __restrict__ hn) {
  int wave = (blockIdx.x * blockDim.x + threadIdx.x) >> 6;
  int lane = threadIdx.x & 63;
  int m0 = wave * 16;
  if (m0 >= NN) return;
  int arow = lane & 15;
  int aoff = (lane >> 4) * 8;
  const ush* ap = h1bf + (size_t)(m0 + arow) * 64 + aoff;
  bf16x8 a0 = *(const bf16x8*)(ap);
  bf16x8 a1 = *(const bf16x8*)(ap + 32);
  const ush* wp = WfragH + lane * 8;
  int ccol = lane & 15;
  int crow = (lane >> 4) * 4;
#pragma unroll
  for (int m = 0; m < 3; ++m) {
    f32x4 acc0 = {0.f, 0.f, 0.f, 0.f};
    f32x4 acc1 = {0.f, 0.f, 0.f, 0.f};
    f32x4 acc2 = {0.f, 0.f, 0.f, 0.f};
    f32x4 acc3 = {0.f, 0.f, 0.f, 0.f};
    const ush* wm = wp + (size_t)m * 8 * 512;
    bf16x8 b0 = *(const bf16x8*)(wm + 0 * 512);
    bf16x8 b1 = *(const bf16x8*)(wm + 1 * 512);
    bf16x8 b2 = *(const bf16x8*)(wm + 2 * 512);
    bf16x8 b3 = *(const bf16x8*)(wm + 3 * 512);
    acc0 = __builtin_amdgcn_mfma_f32_16x16x32_bf16(a0, b0, acc0, 0, 0, 0);
    acc1 = __builtin_amdgcn_mfma_f32_16x16x32_bf16(a0, b1, acc1, 0, 0, 0);
    acc2 = __builtin_amdgcn_mfma_f32_16x16x32_bf16(a0, b2, acc2, 0, 0, 0);
    acc3 = __builtin_amdgcn_mfma_f32_16x16x32_bf16(a0, b3, acc3, 0, 0, 0);
    b0 = *(const bf16x8*)(wm + 4 * 512);
    b1 = *(const bf16x8*)(wm + 5 * 512);
    b2 = *(const bf16x8*)(wm + 6 * 512);
    b3 = *(const bf16x8*)(wm + 7 * 512);
    acc0 = __builtin_amdgcn_mfma_f32_16x16x32_bf16(a1, b0, acc0, 0, 0, 0);
    acc1 = __builtin_amdgcn_mfma_f32_16x16x32_bf16(a1, b1, acc1, 0, 0, 0);
    acc2 = __builtin_amdgcn_mfma_f32_16x16x32_bf16(a1, b2, acc2, 0, 0, 0);
    acc3 = __builtin_amdgcn_mfma_f32_16x16x32_bf16(a1, b3, acc3, 0, 0, 0);
    ush* outm = (m == 0) ? hs : (m == 1) ? hd : hn;
#pragma unroll
    for (int j = 0; j < 4; ++j) {
      ush* op = outm + (size_t)(m0 + crow + j) * 64;
      op[ccol] = f2bf(acc0[j]);
      op[16 + ccol] = f2bf(acc1[j]);
      op[32 + ccol] = f2bf(acc2[j]);
      op[48 + ccol] = f2bf(acc3[j]);
    }
  }
}

// ---------------- layer-2 edge GEMM via MFMA: f116(NEx64 bf16) @ fij(64x64) --------------
__global__ __launch_bounds__(256, 4) void mfma_fout_kernel(
    const ush* __restrict__ f116, const ush* __restrict__ Wfrag2, const float* __restrict__ bias,
    const ush* __restrict__ hs, const ush* __restrict__ hd, const int2* __restrict__ sd_s,
    const float* __restrict__ attn, float* __restrict__ logit) {
  int wave = (blockIdx.x * blockDim.x + threadIdx.x) >> 6;
  int lane = threadIdx.x & 63;
  int m0 = wave * 16;
  if (m0 >= NE) return;
  int arow = lane & 15;
  int aoff = (lane >> 4) * 8;
  const ush* ap = f116 + (size_t)(m0 + arow) * 64 + aoff;
  const ush* wp = Wfrag2 + lane * 8;
  f32x4 acc0 = {0.f, 0.f, 0.f, 0.f};
  f32x4 acc1 = {0.f, 0.f, 0.f, 0.f};
  f32x4 acc2 = {0.f, 0.f, 0.f, 0.f};
  f32x4 acc3 = {0.f, 0.f, 0.f, 0.f};
#pragma unroll
  for (int kk = 0; kk < 2; ++kk) {
    bf16x8 a = *(const bf16x8*)(ap + kk * 32);
    bf16x8 b0 = *(const bf16x8*)(wp + (size_t)(kk * 4 + 0) * 512);
    bf16x8 b1 = *(const bf16x8*)(wp + (size_t)(kk * 4 + 1) * 512);
    bf16x8 b2 = *(const bf16x8*)(wp + (size_t)(kk * 4 + 2) * 512);
    bf16x8 b3 = *(const bf16x8*)(wp + (size_t)(kk * 4 + 3) * 512);
    acc0 = __builtin_amdgcn_mfma_f32_16x16x32_bf16(a, b0, acc0, 0, 0, 0);
    acc1 = __builtin_amdgcn_mfma_f32_16x16x32_bf16(a, b1, acc1, 0, 0, 0);
    acc2 = __builtin_amdgcn_mfma_f32_16x16x32_bf16(a, b2, acc2, 0, 0, 0);
    acc3 = __builtin_amdgcn_mfma_f32_16x16x32_bf16(a, b3, acc3, 0, 0, 0);
  }
  int ccol = lane & 15;
  int crow = (lane >> 4) * 4;
  float av0 = attn[ccol], av1 = attn[16 + ccol], av2 = attn[32 + ccol], av3 = attn[48 + ccol];
  float bv0 = bias[ccol], bv1 = bias[16 + ccol], bv2 = bias[32 + ccol], bv3 = bias[48 + ccol];
#pragma unroll
  for (int j = 0; j < 4; ++j) {
    int r = m0 + crow + j;
    int2 sd = sd_s[r];
    const ush* hsp = hs + (size_t)sd.x * 64;
    const ush* hdp = hd + (size_t)sd.y * 64;
    float f0 = acc0[j] + bf2f(hsp[ccol]) + bf2f(hdp[ccol]) + bv0;
    float f1 = acc1[j] + bf2f(hsp[16 + ccol]) + bf2f(hdp[16 + ccol]) + bv1;
    float f2 = acc2[j] + bf2f(hsp[32 + ccol]) + bf2f(hdp[32 + ccol]) + bv2;
    float f3 = acc3[j] + bf2f(hsp[48 + ccol]) + bf2f(hdp[48 + ccol]) + bv3;
    f0 = f0 >= 0.f ? f0 : 0.01f * f0;
    f1 = f1 >= 0.f ? f1 : 0.01f * f1;
    f2 = f2 >= 0.f ? f2 : 0.01f * f2;
    f3 = f3 >= 0.f ? f3 : 0.01f * f3;
    float p = fmaf(f0, av0, fmaf(f1, av1, fmaf(f2, av2, f3 * av3)));
    p += __shfl_xor(p, 1, 64);
    p += __shfl_xor(p, 2, 64);
    p += __shfl_xor(p, 4, 64);
    p += __shfl_xor(p, 8, 64);
    if (ccol == 0) logit[r] = p;
  }
}

// ---------------- EGAT: gather-aggregate; OSTRIDE lets layer-2 write out[] directly ------
template <bool BF16OUT, int OSTRIDE>
__global__ __launch_bounds__(256, 4) void agg_gather_kernel(
    const ush* __restrict__ hn, const float* __restrict__ logit, const int* __restrict__ rowptr,
    const int* __restrict__ deg, const int2* __restrict__ sd_s, void* __restrict__ hnew) {
  int wave = (blockIdx.x * blockDim.x + threadIdx.x) >> 6;
  int lane = threadIdx.x & 63;
  if (wave >= NN) return;
  int n = wave, d = deg[n], r0 = rowptr[n];
  if (d == 0) {
    if (BF16OUT) ((ush*)hnew)[(size_t)n * OSTRIDE + lane] = 0;
    else ((float*)hnew)[(size_t)n * OSTRIDE + lane] = 0.f;
    return;
  }
  float sum = 0.f, acc0 = 0.f, acc1 = 0.f, acc2 = 0.f, acc3 = 0.f;
  int j = 0;
  for (; j + 3 < d; j += 4) {
    int jj = r0 + j;
    int s0 = sd_s[jj + 0].x, s1 = sd_s[jj + 1].x, s2 = sd_s[jj + 2].x, s3 = sd_s[jj + 3].x;
    float l0 = logit[jj + 0], l1 = logit[jj + 1], l2 = logit[jj + 2], l3 = logit[jj + 3];
    ush h0 = hn[(size_t)s0 * 64 + lane];
    ush h1 = hn[(size_t)s1 * 64 + lane];
    ush h2 = hn[(size_t)s2 * 64 + lane];
    ush h3 = hn[(size_t)s3 * 64 + lane];
    float w0 = __expf(l0), w1 = __expf(l1);
    float w2 = __expf(l2), w3 = __expf(l3);
    sum += (w0 + w1) + (w2 + w3);
    acc0 = fmaf(w0, bf2f(h0), acc0);
    acc1 = fmaf(w1, bf2f(h1), acc1);
    acc2 = fmaf(w2, bf2f(h2), acc2);
    acc3 = fmaf(w3, bf2f(h3), acc3);
  }
  for (; j < d; ++j) {
    int jj = r0 + j;
    float w = __expf(logit[jj]);
    sum += w;
    acc0 = fmaf(w, bf2f(hn[(size_t)sd_s[jj].x * 64 + lane]), acc0);
  }
  float r = ((acc0 + acc1) + (acc2 + acc3)) / sum;
  if (BF16OUT) ((ush*)hnew)[(size_t)n * OSTRIDE + lane] = f2bf(r);
  else ((float*)hnew)[(size_t)n * OSTRIDE + lane] = r;
}

// ---------------- NNConv fused: gather G into LDS, MFMA GEMM from LDS -------------------
__global__ __launch_bounds__(256, 4) void nnconv_fused_kernel(
    const ush* __restrict__ face16, const ush* __restrict__ ef16,
    const int* __restrict__ rowptr, const int* __restrict__ deg,
    const int2* __restrict__ sd_s, const ush* __restrict__ Wfrag,
    float* __restrict__ sArr) {
  __shared__ ush Gs[16][552];
  int wid = threadIdx.x >> 6;
  int lane = threadIdx.x & 63;
  int nbase = blockIdx.x * 16;  // NN % 16 == 0
  int k4 = lane >> 2, ib = lane & 3;
  for (int q = 0; q < 4; ++q) {
    int row = wid * 4 + q;
    int n = nbase + row;
    int d = deg[n], r0 = rowptr[n];
    float g[8], fs[8];
#pragma unroll
    for (int u = 0; u < 8; ++u) { g[u] = 0.f; fs[u] = 0.f; }
    int j = 0;
    for (; j + 1 < d; j += 2) {
      int jj = r0 + j;
      int s0 = sd_s[jj].x, s1 = sd_s[jj + 1].x;
      float ev0 = bf2f(ef16[(size_t)jj * 16 + k4]);
      float ev1 = bf2f(ef16[(size_t)(jj + 1) * 16 + k4]);
      uint4 u0 = *(const uint4*)(face16 + (size_t)s0 * 32 + ib * 8);
      uint4 u1 = *(const uint4*)(face16 + (size_t)s1 * 32 + ib * 8);
      float fa0[8], fa1[8];
      unp8(u0, fa0);
      unp8(u1, fa1);
#pragma unroll
      for (int u = 0; u < 8; ++u) {
        g[u] = fmaf(ev0, fa0[u], g[u]);
        g[u] = fmaf(ev1, fa1[u], g[u]);
      }
      if (k4 == 0) {
#pragma unroll
        for (int u = 0; u < 8; ++u) fs[u] += fa0[u] + fa1[u];
      }
    }
    if (j < d) {
      int jj = r0 + j;
      float ev0 = bf2f(ef16[(size_t)jj * 16 + k4]);
      uint4 u0 = *(const uint4*)(face16 + (size_t)sd_s[jj].x * 32 + ib * 8);
      float fa0[8];
      unp8(u0, fa0);
#pragma unroll
      for (int u = 0; u < 8; ++u) g[u] = fmaf(ev0, fa0[u], g[u]);
      if (k4 == 0) {
#pragma unroll
        for (int u = 0; u < 8; ++u) fs[u] += fa0[u];
      }
    }
    uint4 pv;
    pv.x = pack2(g[0], g[1]); pv.y = pack2(g[2], g[3]);
    pv.z = pack2(g[4], g[5]); pv.w = pack2(g[6], g[7]);
    *(uint4*)&Gs[row][lane * 8] = pv;
    if (k4 == 0) {
      uint4 fv;
      fv.x = pack2(fs[0], fs[1]); fv.y = pack2(fs[2], fs[3]);
      fv.z = pack2(fs[4], fs[5]); fv.w = pack2(fs[6], fs[7]);
      *(uint4*)&Gs[row][512 + ib * 8] = fv;
    }
  }
  __syncthreads();
  if (wid < 2) {
    int arow = lane & 15;
    int aoff = (lane >> 4) * 8;
    const ush* wp = Wfrag + lane * 8;
    f32x4 acc = {0.f, 0.f, 0.f, 0.f};
#pragma unroll 4
    for (int kk = 0; kk < 17; ++kk) {
      bf16x8 a = *(const bf16x8*)&Gs[arow][kk * 32 + aoff];
      bf16x8 b = *(const bf16x8*)(wp + (size_t)(kk * 2 + wid) * 512);
      acc = __builtin_amdgcn_mfma_f32_16x16x32_bf16(a, b, acc, 0, 0, 0);
    }
    int ccol = lane & 15;
    int crow = (lane >> 4) * 4;
#pragma unroll
    for (int j = 0; j < 4; ++j) {
      int r = nbase + crow + j;
      sArr[(size_t)r * 32 + wid * 16 + ccol] = acc[j];
    }
  }
}

// ---------------- combine node_features + gate logit; v0 read back from out --------------
__global__ void combine_gate_kernel(const float* __restrict__ sArr,
                                    const int* __restrict__ deg, const float* __restrict__ nn_bias,
                                    const float* __restrict__ gate_w, const float* __restrict__ gate_b,
                                    float* __restrict__ out, float* __restrict__ g) {
  int wave = (blockIdx.x * blockDim.x + threadIdx.x) >> 6;
  int lane = threadIdx.x & 63;
  if (wave >= NN) return;
  int n = wave;
  float v0 = out[(size_t)n * 128 + lane];
  int c1 = lane + 64;
  float v1 = (c1 < 96)
                 ? sArr[(size_t)n * 32 + (c1 - 64)] / fmaxf((float)deg[n], 1.0f) + nn_bias[c1 - 64]
                 : 0.f;
  out[(size_t)n * 128 + c1] = v1;
  float p = v0 * gate_w[lane] + ((c1 < 96) ? v1 * gate_w[c1] : 0.f);
#pragma unroll
  for (int off = 32; off; off >>= 1) p += __shfl_xor(p, off, 64);
  if (lane == 0) g[n] = p + gate_b[0];
}

// ---------------- max over g (block-reduced, 1 atomic per block; 128 blocks) ----------------
__global__ void gate_max_kernel(const float* __restrict__ g, unsigned* __restrict__ gmax) {
  int tid = blockIdx.x * blockDim.x + threadIdx.x;
  int stride = gridDim.x * blockDim.x;
  float v = -3.0e38f;
  for (int n = tid; n < NN; n += stride) v = fmaxf(v, g[n]);
#pragma unroll
  for (int off = 32; off; off >>= 1) v = fmaxf(v, __shfl_xor(v, off, 64));
  __shared__ float sm[4];
  int lane = threadIdx.x & 63, wid = threadIdx.x >> 6;
  if (lane == 0) sm[wid] = v;
  __syncthreads();
  if (threadIdx.x == 0) {
    float m = fmaxf(fmaxf(sm[0], sm[1]), fmaxf(sm[2], sm[3]));
    atomicMax(gmax, ord_enc(m));
  }
}

// ---------------- pooling: exp + weighted accumulate into per-row-stream partials --------
__global__ __launch_bounds__(256, 4) void pool_exp_kernel(
    const float* __restrict__ nf, const float* __restrict__ g, const unsigned* __restrict__ gmax,
    float* __restrict__ pacc, float* __restrict__ wsb) {
  int o = threadIdx.x & 127;
  int half = threadIdx.x >> 7;
  int ri = blockIdx.x * 2 + half;   // 0 .. 2*PB-1
  float m = ord_dec(*gmax);
  float acc0 = 0.f, acc1 = 0.f, ws = 0.f;
  int n = ri;
  const int STR = PB * 2;
  for (; n + STR < NN; n += STR * 2) {
    float w0 = __expf(g[n] - m);
    float w1 = __expf(g[n + STR] - m);
    float v0 = nf[(size_t)n * 128 + o];
    float v1 = nf[(size_t)(n + STR) * 128 + o];
    ws += w0 + w1;
    acc0 = fmaf(w0, v0, acc0);
    acc1 = fmaf(w1, v1, acc1);
  }
  if (n < NN) {
    float w = __expf(g[n] - m);
    ws += w;
    acc0 = fmaf(w, nf[(size_t)n * 128 + o], acc0);
  }
  pacc[(size_t)ri * 128 + o] = acc0 + acc1;
  if (o == 0) wsb[ri] = ws;
}

__global__ void pool_reduce_kernel(const float* __restrict__ pacc, const float* __restrict__ wsb,
                                   float* __restrict__ gacc, float* __restrict__ gsum) {
  int b = blockIdx.x;
  int t = threadIdx.x;  // 256
  float v = 0.f;
  if (b < 128) {
    for (int ri = t; ri < PB * 2; ri += 256) v += pacc[(size_t)ri * 128 + b];
  } else {
    for (int ri = t; ri < PB * 2; ri += 256) v += wsb[ri];
  }
#pragma unroll
  for (int off = 32; off; off >>= 1) v += __shfl_xor(v, off, 64);
  __shared__ float sm[4];
  int lane = t & 63, wid = t >> 6;
  if (lane == 0) sm[wid] = v;
  __syncthreads();
  if (t == 0) {
    float s = (sm[0] + sm[1]) + (sm[2] + sm[3]);
    if (b < 128) gacc[b] = s;
    else gsum[0] = s;
  }
}

__global__ void finalize_kernel(const float* __restrict__ gacc, const float* __restrict__ gsum,
                                float* __restrict__ out) {
  int o = threadIdx.x;
  if (o < 128) out[(size_t)NN * 128 + o] = gacc[o] / gsum[0];
}

extern "C" void kernel_launch(void* const* d_in, const int* in_sizes, int n_in,
                              void* d_out, int out_size, void* d_ws, size_t ws_size,
                              hipStream_t stream) {
  const float* face    = (const float*)d_in[0];
  const float* ef      = (const float*)d_in[1];
  const float* fp_w    = (const float*)d_in[2];
  const float* fp_b    = (const float*)d_in[3];
  const float* ep_w    = (const float*)d_in[4];
  const float* ep_b    = (const float*)d_in[5];
  const float* nn_w    = (const float*)d_in[6];
  const float* nn_b    = (const float*)d_in[7];
  const float* nn_bias = (const float*)d_in[8];
  const float* gate_w  = (const float*)d_in[9];
  const float* gate_b  = (const float*)d_in[10];
  const int*   src     = (const int*)d_in[11];
  const int*   dst     = (const int*)d_in[12];
  const float* e1_attn = (const float*)d_in[17];
  const float* e2_ni   = (const float*)d_in[19];
  const float* e2_nj   = (const float*)d_in[20];
  const float* e2_fij  = (const float*)d_in[21];
  const float* e2_attn = (const float*)d_in[23];
  const float* e2_bias = (const float*)d_in[24];
  float* out = (float*)d_out;

  char* p = (char*)d_ws;
  auto alloc = [&](size_t nfloats) {
    float* r = (float*)p;
    p += ((nfloats * 4 + 255) / 256) * 256;
    return r;
  };
  ush* h1bf = (ush*)alloc((size_t)NN * 32);   // layer-1 output (bf16)
  ush* hs16 = (ush*)alloc((size_t)NN * 32);   // NN*64 bf16
  ush* hd16 = (ush*)alloc((size_t)NN * 32);
  ush* hn16 = (ush*)alloc((size_t)NN * 32);
  ush* f116 = (ush*)alloc((size_t)NE * 32);   // NE*64 bf16 (dst-sorted order)
  float* logit = alloc(NE);                   // dst-sorted order
  float* sArr  = alloc((size_t)NN * 32);
  float* g     = alloc(NN);
  float* gacc  = alloc(128);
  float* gsum  = alloc(1);
  unsigned* gmax = (unsigned*)alloc(1);
  float* fold  = alloc(7424);
  ush* Wfrag   = (ush*)alloc(17408 / 2);      // nn MFMA B-fragments
  ush* Wfrag2  = (ush*)alloc(4096 / 2);       // e2_fij MFMA B-fragments
  ush* WfragH  = (ush*)alloc(12288 / 2);      // e2_{ni,nj,node} MFMA B-fragments
  ush* Wf1frag = (ush*)alloc(2048 / 2);       // layer-1 folded fij MFMA B-fragments
  ush* WfragH1 = (ush*)alloc(6144 / 2);       // layer-1 folded {ni,nj,node} B-fragments
  ush* face16  = (ush*)alloc((size_t)NN * 16);  // NN*32 bf16
  ush* ef16    = (ush*)alloc((size_t)NE * 8);   // NE*16 bf16 (dst-sorted, no padding)
  float* pacc  = alloc((size_t)PB * 2 * 128); // pooling partials
  float* wsb   = alloc(PB * 2);
  // dst-CSR
  int* deg    = (int*)alloc(NN);
  int* rowptr = (int*)alloc(NN);
  int* cursor = (int*)alloc(NN);
  int* partial = (int*)alloc(256);
  int2* sd_s  = (int2*)alloc((size_t)NE * 2);  // packed (src,dst), dst-sorted

  const int B = 256;
  const int NB256 = cdiv(NN, 256);

  // ---- CSR build (dst-sorted) + fused edge permutation (bf16 only) ----
  hipMemsetAsync(deg, 0, NN * 4, stream);
  deg_kernel<<<cdiv(NE, B), B, 0, stream>>>(dst, deg);
  scan1_kernel<<<NB256, 256, 0, stream>>>(deg, rowptr, partial);
  scan2_kernel<<<1, 256, 0, stream>>>(partial, NB256);
  scan3_kernel<<<NB256, 256, 0, stream>>>(rowptr, partial, cursor);
  scatter_dst_kernel<<<cdiv(NE, B), B, 0, stream>>>(src, dst, ef, cursor, sd_s, ef16);

  // ---- weight prep: fold, then merged fragment packs + face convert ----
  fold_kernel<<<29, B, 0, stream>>>(fp_w, fp_b, ep_w, ep_b,
                                    (const float*)d_in[15], (const float*)d_in[18],
                                    (const float*)d_in[13], (const float*)d_in[14],
                                    (const float*)d_in[16], fold);
  prep_rest_kernel<<<cdiv(41984 + NN * 8, B), B, 0, stream>>>(
      fold, nn_w, nn_b, e2_fij, e2_ni, e2_nj, (const float*)d_in[22], face,
      Wf1frag, WfragH1, Wfrag, Wfrag2, WfragH, face16);

  // ---- EGAT layer 1 (all matmuls on matrix cores) ----
  mfma_hproj1_kernel<<<cdiv(NN * 4, B), B, 0, stream>>>(face16, WfragH1, fold, hs16, hd16, hn16);
  mfma_fout1_kernel<<<cdiv(NE * 4, B), B, 0, stream>>>(ef16, Wf1frag, fold, hs16, hd16,
                                                       sd_s, e1_attn, f116, logit);
  agg_gather_kernel<true, 64><<<cdiv(NN * 64, B), B, 0, stream>>>(hn16, logit, rowptr, deg,
                                                                  sd_s, h1bf);

  // ---- EGAT layer 2 (hproj + edge GEMM on matrix cores) ----
  mfma_hproj_kernel<<<cdiv(NN * 4, B), B, 0, stream>>>(h1bf, WfragH, hs16, hd16, hn16);
  mfma_fout_kernel<<<cdiv(NE * 4, B), B, 0, stream>>>(f116, Wfrag2, e2_bias, hs16, hd16,
                                                      sd_s, e2_attn, logit);
  // layer-2 aggregate writes Gf directly into out[:, 0:64]
  agg_gather_kernel<false, 128><<<cdiv(NN * 64, B), B, 0, stream>>>(hn16, logit, rowptr, deg,
                                                                    sd_s, out);

  // ---- NNConv fused (G lives only in LDS; face gathered as bf16) ----
  nnconv_fused_kernel<<<NN / 16, B, 0, stream>>>(face16, ef16, rowptr, deg, sd_s, Wfrag, sArr);

  // ---- combine node features + gate logits; separate 128-block max (atomics bounded) ----
  hipMemsetAsync(gmax, 0, 4, stream);
  combine_gate_kernel<<<cdiv(NN * 64, B), B, 0, stream>>>(sArr, deg, nn_bias, gate_w,
                                                          gate_b, out, g);
  gate_max_kernel<<<128, B, 0, stream>>>(g, gmax);
  pool_exp_kernel<<<PB, B, 0, stream>>>(out, g, gmax, pacc, wsb);
  pool_reduce_kernel<<<129, B, 0, stream>>>(pacc, wsb, gacc, gsum);
  finalize_kernel<<<1, 128, 0, stream>>>(gacc, gsum, out);
}

// Round 30
// 229.864 us; speedup vs baseline: 1.7050x; 1.0055x over previous
//
#include <hip/hip_runtime.h>

#define NN 60000
#define NE 300000
#define PB 768
typedef unsigned short ush;
typedef __attribute__((ext_vector_type(8))) short bf16x8;
typedef __attribute__((ext_vector_type(4))) float f32x4;

static inline int cdiv(int a, int b) { return (a + b - 1) / b; }

__device__ inline unsigned ord_enc(float x) {
  unsigned u = __float_as_uint(x);
  return (u & 0x80000000u) ? ~u : (u | 0x80000000u);
}
__device__ inline float ord_dec(unsigned u) {
  return __uint_as_float((u & 0x80000000u) ? (u & 0x7fffffffu) : ~u);
}
__device__ inline float bf2f(unsigned u16) { return __uint_as_float(u16 << 16); }
__device__ inline ush f2bf(float x) {
  unsigned u = __float_as_uint(x);
  return (ush)((u + 0x7FFFu + ((u >> 16) & 1u)) >> 16);
}
__device__ inline unsigned pack2(float lo, float hi) {
  return ((unsigned)f2bf(hi) << 16) | (unsigned)f2bf(lo);
}
__device__ inline void unp8(uint4 u, float* f) {
  f[0] = bf2f(u.x & 0xffff); f[1] = bf2f(u.x >> 16);
  f[2] = bf2f(u.y & 0xffff); f[3] = bf2f(u.y >> 16);
  f[4] = bf2f(u.z & 0xffff); f[5] = bf2f(u.z >> 16);
  f[6] = bf2f(u.w & 0xffff); f[7] = bf2f(u.w >> 16);
}

// ================= CSR build (dst-sorted) =================
__global__ void deg_kernel(const int* __restrict__ key, int* __restrict__ deg) {
  int e = blockIdx.x * blockDim.x + threadIdx.x;
  if (e < NE) atomicAdd(deg + key[e], 1);
}

__global__ void scan1_kernel(const int* __restrict__ deg, int* __restrict__ rowptr,
                             int* __restrict__ partial) {
  __shared__ int s[256];
  int i = blockIdx.x * 256 + threadIdx.x;
  int v = (i < NN) ? deg[i] : 0;
  s[threadIdx.x] = v;
  __syncthreads();
  for (int off = 1; off < 256; off <<= 1) {
    int t = (threadIdx.x >= off) ? s[threadIdx.x - off] : 0;
    __syncthreads();
    s[threadIdx.x] += t;
    __syncthreads();
  }
  if (i < NN) rowptr[i] = s[threadIdx.x] - v;
  if (threadIdx.x == 255) partial[blockIdx.x] = s[255];
}

__global__ void scan2_kernel(int* __restrict__ partial, int nb) {
  __shared__ int s[256];
  int v = (threadIdx.x < nb) ? partial[threadIdx.x] : 0;
  s[threadIdx.x] = v;
  __syncthreads();
  for (int off = 1; off < 256; off <<= 1) {
    int t = (threadIdx.x >= off) ? s[threadIdx.x - off] : 0;
    __syncthreads();
    s[threadIdx.x] += t;
    __syncthreads();
  }
  if (threadIdx.x < nb) partial[threadIdx.x] = s[threadIdx.x] - v;
}

__global__ void scan3_kernel(int* __restrict__ rowptr, const int* __restrict__ partial,
                             int* __restrict__ cursor) {
  int i = blockIdx.x * 256 + threadIdx.x;
  if (i < NN) {
    int r = rowptr[i] + partial[blockIdx.x];
    rowptr[i] = r;
    cursor[i] = r;
  }
}

// scatter + ef permutation fused; emits ef16 (NEx16 bf16) + packed (src,dst) int2
__global__ void scatter_dst_kernel(const int* __restrict__ src, const int* __restrict__ dst,
                                   const float* __restrict__ ef, int* __restrict__ cursor,
                                   int2* __restrict__ sd_s, ush* __restrict__ ef16) {
  int e = blockIdx.x * blockDim.x + threadIdx.x;
  if (e >= NE) return;
  int d = dst[e];
  int j = atomicAdd(cursor + d, 1);
  sd_s[j] = make_int2(src[e], d);
  const float4* ep = (const float4*)(ef + (size_t)e * 16);
  float4 a = ep[0], b = ep[1], c = ep[2], dd = ep[3];
  uint4* bp = (uint4*)(ef16 + (size_t)j * 16);
  uint4 p0, p1;
  p0.x = pack2(a.x, a.y); p0.y = pack2(a.z, a.w);
  p0.z = pack2(b.x, b.y); p0.w = pack2(b.z, b.w);
  p1.x = pack2(c.x, c.y); p1.y = pack2(c.z, c.w);
  p1.z = pack2(dd.x, dd.y); p1.w = pack2(dd.z, dd.w);
  bp[0] = p0; bp[1] = p1;
}

// ---------------- fold: precompute folded weight products (7424 dots of length 64) -------
__global__ void fold_kernel(const float* __restrict__ fp_w, const float* __restrict__ fp_b,
                            const float* __restrict__ ep_w, const float* __restrict__ ep_b,
                            const float* __restrict__ fij, const float* __restrict__ ebias,
                            const float* __restrict__ ni, const float* __restrict__ nj,
                            const float* __restrict__ node, float* __restrict__ fold) {
  int t = blockIdx.x * blockDim.x + threadIdx.x;
  if (t >= 7424) return;
  int o = t & 63;
  const float* A;
  const float* B;
  float init = 0.f;
  if (t < 1024)      { A = ep_w + (size_t)(t >> 6) * 64; B = fij + o; }
  else if (t < 1088) { A = ep_b; B = fij + o; init = ebias[o]; }
  else if (t < 3136) { A = fp_w + (size_t)((t - 1088) >> 6) * 64; B = ni + o; }
  else if (t < 5184) { A = fp_w + (size_t)((t - 3136) >> 6) * 64; B = nj + o; }
  else if (t < 7232) { A = fp_w + (size_t)((t - 5184) >> 6) * 64; B = node + o; }
  else if (t < 7296) { A = fp_b; B = ni + o; }
  else if (t < 7360) { A = fp_b; B = nj + o; }
  else               { A = fp_b; B = node + o; }
  float a = init;
  for (int i = 0; i < 64; ++i) a = fmaf(A[i], B[(size_t)i * 64], a);
  fold[t] = a;
}

// ---------------- merged prep: fold1_frag | nnwt | fij | hproj_frag | face16 -------------
__global__ void prep_rest_kernel(const float* __restrict__ fold, const float* __restrict__ nn_w,
                                 const float* __restrict__ nn_b, const float* __restrict__ fij,
                                 const float* __restrict__ ni, const float* __restrict__ nj,
                                 const float* __restrict__ node, const float* __restrict__ face,
                                 ush* __restrict__ Wf1frag, ush* __restrict__ WfragH1,
                                 ush* __restrict__ Wfrag, ush* __restrict__ Wfrag2,
                                 ush* __restrict__ WfragH, ush* __restrict__ face16) {
  int t = blockIdx.x * blockDim.x + threadIdx.x;
  if (t < 8192) {
    if (t < 2048) {
      int i = t & 7, lane = (t >> 3) & 63, ct = t >> 9;
      int k = (lane >> 4) * 8 + i;
      int o = ct * 16 + (lane & 15);
      Wf1frag[t] = (k < 16) ? f2bf(fold[(size_t)k * 64 + o]) : 0;
    } else {
      int idx = t - 2048;
      int i = idx & 7, lane = (idx >> 3) & 63, ct = (idx >> 9) & 3, m = idx >> 11;
      int k = (lane >> 4) * 8 + i;
      int o = ct * 16 + (lane & 15);
      WfragH1[idx] = f2bf(fold[1088 + (size_t)m * 2048 + (size_t)k * 64 + o]);
    }
  } else if (t < 25600) {
    int u = t - 8192;
    int i = u & 7, lane = (u >> 3) & 63, ct = (u >> 9) & 1, kk = u >> 10;
    int k = kk * 32 + (lane >> 4) * 8 + i;
    int o = ct * 16 + (lane & 15);
    float v = (k < 512) ? nn_w[(size_t)(k >> 5) * 1024 + (k & 31) * 32 + o]
                        : nn_b[(k - 512) * 32 + o];
    Wfrag[u] = f2bf(v);
  } else if (t < 29696) {
    int u = t - 25600;
    int i = u & 7, lane = (u >> 3) & 63, ct = (u >> 9) & 3, kk = u >> 11;
    int k = kk * 32 + (lane >> 4) * 8 + i;
    int o = ct * 16 + (lane & 15);
    Wfrag2[u] = f2bf(fij[(size_t)k * 64 + o]);
  } else if (t < 41984) {
    int u = t - 29696;
    int i = u & 7, lane = (u >> 3) & 63, ct = (u >> 9) & 3, kk = (u >> 11) & 1, m = u >> 12;
    int k = kk * 32 + (lane >> 4) * 8 + i;
    int o = ct * 16 + (lane & 15);
    const float* W = (m == 0) ? ni : (m == 1) ? nj : node;
    WfragH[u] = f2bf(W[(size_t)k * 64 + o]);
  } else if (t < 41984 + NN * 8) {
    int u = t - 41984;
    const float4 v = ((const float4*)face)[u];
    ((uint2*)face16)[u] = make_uint2(pack2(v.x, v.y), pack2(v.z, v.w));
  }
}

// ---------------- layer-1 hproj via MFMA: face16(NNx32) @ folded {ni,nj,node}(32x64) -----
__global__ __launch_bounds__(256, 4) void mfma_hproj1_kernel(
    const ush* __restrict__ face16, const ush* __restrict__ WfragH1,
    const float* __restrict__ fold, ush* __restrict__ hs, ush* __restrict__ hd,
    ush* __restrict__ hn) {
  int wave = (blockIdx.x * blockDim.x + threadIdx.x) >> 6;
  int lane = threadIdx.x & 63;
  int m0 = wave * 16;
  if (m0 >= NN) return;
  int arow = lane & 15;
  int aoff = (lane >> 4) * 8;
  bf16x8 a = *(const bf16x8*)(face16 + (size_t)(m0 + arow) * 32 + aoff);
  int ccol = lane & 15;
  int crow = (lane >> 4) * 4;
#pragma unroll
  for (int m = 0; m < 3; ++m) {
    const ush* wm = WfragH1 + (size_t)m * 2048 + lane * 8;
    bf16x8 b0 = *(const bf16x8*)(wm + 0 * 512);
    bf16x8 b1 = *(const bf16x8*)(wm + 1 * 512);
    bf16x8 b2 = *(const bf16x8*)(wm + 2 * 512);
    bf16x8 b3 = *(const bf16x8*)(wm + 3 * 512);
    f32x4 acc0 = {0.f, 0.f, 0.f, 0.f};
    f32x4 acc1 = {0.f, 0.f, 0.f, 0.f};
    f32x4 acc2 = {0.f, 0.f, 0.f, 0.f};
    f32x4 acc3 = {0.f, 0.f, 0.f, 0.f};
    acc0 = __builtin_amdgcn_mfma_f32_16x16x32_bf16(a, b0, acc0, 0, 0, 0);
    acc1 = __builtin_amdgcn_mfma_f32_16x16x32_bf16(a, b1, acc1, 0, 0, 0);
    acc2 = __builtin_amdgcn_mfma_f32_16x16x32_bf16(a, b2, acc2, 0, 0, 0);
    acc3 = __builtin_amdgcn_mfma_f32_16x16x32_bf16(a, b3, acc3, 0, 0, 0);
    float bv0 = fold[7232 + m * 64 + ccol];
    float bv1 = fold[7232 + m * 64 + 16 + ccol];
    float bv2 = fold[7232 + m * 64 + 32 + ccol];
    float bv3 = fold[7232 + m * 64 + 48 + ccol];
    ush* outm = (m == 0) ? hs : (m == 1) ? hd : hn;
#pragma unroll
    for (int j = 0; j < 4; ++j) {
      ush* op = outm + (size_t)(m0 + crow + j) * 64;
      op[ccol] = f2bf(acc0[j] + bv0);
      op[16 + ccol] = f2bf(acc1[j] + bv1);
      op[32 + ccol] = f2bf(acc2[j] + bv2);
      op[48 + ccol] = f2bf(acc3[j] + bv3);
    }
  }
}

// ---------------- layer-1 edge GEMM via MFMA: ef16(NEx16) @ Wf1(32x64, folded, k>=16 = 0) -
__global__ __launch_bounds__(256, 4) void mfma_fout1_kernel(
    const ush* __restrict__ ef16, const ush* __restrict__ Wf1frag, const float* __restrict__ fold,
    const ush* __restrict__ hs, const ush* __restrict__ hd, const int2* __restrict__ sd_s,
    const float* __restrict__ attn, ush* __restrict__ f116, float* __restrict__ logit) {
  int wave = (blockIdx.x * blockDim.x + threadIdx.x) >> 6;
  int lane = threadIdx.x & 63;
  int m0 = wave * 16;
  if (m0 >= NE) return;
  int arow = lane & 15;
  int aoff = (lane >> 4) * 8;
  bf16x8 a = {0, 0, 0, 0, 0, 0, 0, 0};
  if (aoff < 16) a = *(const bf16x8*)(ef16 + (size_t)(m0 + arow) * 16 + aoff);
  const ush* wp = Wf1frag + lane * 8;
  bf16x8 b0 = *(const bf16x8*)(wp + 0 * 512);
  bf16x8 b1 = *(const bf16x8*)(wp + 1 * 512);
  bf16x8 b2 = *(const bf16x8*)(wp + 2 * 512);
  bf16x8 b3 = *(const bf16x8*)(wp + 3 * 512);
  f32x4 acc0 = {0.f, 0.f, 0.f, 0.f};
  f32x4 acc1 = {0.f, 0.f, 0.f, 0.f};
  f32x4 acc2 = {0.f, 0.f, 0.f, 0.f};
  f32x4 acc3 = {0.f, 0.f, 0.f, 0.f};
  acc0 = __builtin_amdgcn_mfma_f32_16x16x32_bf16(a, b0, acc0, 0, 0, 0);
  acc1 = __builtin_amdgcn_mfma_f32_16x16x32_bf16(a, b1, acc1, 0, 0, 0);
  acc2 = __builtin_amdgcn_mfma_f32_16x16x32_bf16(a, b2, acc2, 0, 0, 0);
  acc3 = __builtin_amdgcn_mfma_f32_16x16x32_bf16(a, b3, acc3, 0, 0, 0);
  int ccol = lane & 15;
  int crow = (lane >> 4) * 4;
  float av0 = attn[ccol], av1 = attn[16 + ccol], av2 = attn[32 + ccol], av3 = attn[48 + ccol];
  float bv0 = fold[1024 + ccol], bv1 = fold[1024 + 16 + ccol];
  float bv2 = fold[1024 + 32 + ccol], bv3 = fold[1024 + 48 + ccol];
#pragma unroll
  for (int j = 0; j < 4; ++j) {
    int r = m0 + crow + j;
    int2 sd = sd_s[r];
    const ush* hsp = hs + (size_t)sd.x * 64;
    const ush* hdp = hd + (size_t)sd.y * 64;
    float f0 = acc0[j] + bf2f(hsp[ccol]) + bf2f(hdp[ccol]) + bv0;
    float f1 = acc1[j] + bf2f(hsp[16 + ccol]) + bf2f(hdp[16 + ccol]) + bv1;
    float f2 = acc2[j] + bf2f(hsp[32 + ccol]) + bf2f(hdp[32 + ccol]) + bv2;
    float f3 = acc3[j] + bf2f(hsp[48 + ccol]) + bf2f(hdp[48 + ccol]) + bv3;
    f0 = f0 >= 0.f ? f0 : 0.01f * f0;
    f1 = f1 >= 0.f ? f1 : 0.01f * f1;
    f2 = f2 >= 0.f ? f2 : 0.01f * f2;
    f3 = f3 >= 0.f ? f3 : 0.01f * f3;
    ush* fp = f116 + (size_t)r * 64;
    fp[ccol] = f2bf(f0);
    fp[16 + ccol] = f2bf(f1);
    fp[32 + ccol] = f2bf(f2);
    fp[48 + ccol] = f2bf(f3);
    float p = fmaf(f0, av0, fmaf(f1, av1, fmaf(f2, av2, f3 * av3)));
    p += __shfl_xor(p, 1, 64);
    p += __shfl_xor(p, 2, 64);
    p += __shfl_xor(p, 4, 64);
    p += __shfl_xor(p, 8, 64);
    if (ccol == 0) logit[r] = p;
  }
}

// ---------------- layer-2 hproj via MFMA: h1bf(NNx64) @ {ni,nj,node}(64x64) --------------
__global__ __launch_bounds__(256, 4) void mfma_hproj_kernel(
    const ush* __restrict__ h1bf, const ush* __restrict__ WfragH, ush* __restrict__ hs,
    ush* __restrict__ hd, ush* __restrict__ hn) {
  int wave = (blockIdx.x * blockDim.x + threadIdx.x) >> 6;
  int lane = threadIdx.x & 63;
  int m0 = wave * 16;
  if (m0 >= NN) return;
  int arow = lane & 15;
  int aoff = (lane >> 4) * 8;
  const ush* ap = h1bf + (size_t)(m0 + arow) * 64 + aoff;
  bf16x8 a0 = *(const bf16x8*)(ap);
  bf16x8 a1 = *(const bf16x8*)(ap + 32);
  const ush* wp = WfragH + lane * 8;
  int ccol = lane & 15;
  int crow = (lane >> 4) * 4;
#pragma unroll
  for (int m = 0; m < 3; ++m) {
    f32x4 acc0 = {0.f, 0.f, 0.f, 0.f};
    f32x4 acc1 = {0.f, 0.f, 0.f, 0.f};
    f32x4 acc2 = {0.f, 0.f, 0.f, 0.f};
    f32x4 acc3 = {0.f, 0.f, 0.f, 0.f};
    const ush* wm = wp + (size_t)m * 8 * 512;
    bf16x8 b0 = *(const bf16x8*)(wm + 0 * 512);
    bf16x8 b1 = *(const bf16x8*)(wm + 1 * 512);
    bf16x8 b2 = *(const bf16x8*)(wm + 2 * 512);
    bf16x8 b3 = *(const bf16x8*)(wm + 3 * 512);
    acc0 = __builtin_amdgcn_mfma_f32_16x16x32_bf16(a0, b0, acc0, 0, 0, 0);
    acc1 = __builtin_amdgcn_mfma_f32_16x16x32_bf16(a0, b1, acc1, 0, 0, 0);
    acc2 = __builtin_amdgcn_mfma_f32_16x16x32_bf16(a0, b2, acc2, 0, 0, 0);
    acc3 = __builtin_amdgcn_mfma_f32_16x16x32_bf16(a0, b3, acc3, 0, 0, 0);
    b0 = *(const bf16x8*)(wm + 4 * 512);
    b1 = *(const bf16x8*)(wm + 5 * 512);
    b2 = *(const bf16x8*)(wm + 6 * 512);
    b3 = *(const bf16x8*)(wm + 7 * 512);
    acc0 = __builtin_amdgcn_mfma_f32_16x16x32_bf16(a1, b0, acc0, 0, 0, 0);
    acc1 = __builtin_amdgcn_mfma_f32_16x16x32_bf16(a1, b1, acc1, 0, 0, 0);
    acc2 = __builtin_amdgcn_mfma_f32_16x16x32_bf16(a1, b2, acc2, 0, 0, 0);
    acc3 = __builtin_amdgcn_mfma_f32_16x16x32_bf16(a1, b3, acc3, 0, 0, 0);
    ush* outm = (m == 0) ? hs : (m == 1) ? hd : hn;
#pragma unroll
    for (int j = 0; j < 4; ++j) {
      ush* op = outm + (size_t)(m0 + crow + j) * 64;
      op[ccol] = f2bf(acc0[j]);
      op[16 + ccol] = f2bf(acc1[j]);
      op[32 + ccol] = f2bf(acc2[j]);
      op[48 + ccol] = f2bf(acc3[j]);
    }
  }
}

// ---------------- layer-2 edge GEMM via MFMA: f116(NEx64 bf16) @ fij(64x64) --------------
__global__ __launch_bounds__(256, 4) void mfma_fout_kernel(
    const ush* __restrict__ f116, const ush* __restrict__ Wfrag2, const float* __restrict__ bias,
    const ush* __restrict__ hs, const ush* __restrict__ hd, const int2* __restrict__ sd_s,
    const float* __restrict__ attn, float* __restrict__ logit) {
  int wave = (blockIdx.x * blockDim.x + threadIdx.x) >> 6;
  int lane = threadIdx.x & 63;
  int m0 = wave * 16;
  if (m0 >= NE) return;
  int arow = lane & 15;
  int aoff = (lane >> 4) * 8;
  const ush* ap = f116 + (size_t)(m0 + arow) * 64 + aoff;
  const ush* wp = Wfrag2 + lane * 8;
  f32x4 acc0 = {0.f, 0.f, 0.f, 0.f};
  f32x4 acc1 = {0.f, 0.f, 0.f, 0.f};
  f32x4 acc2 = {0.f, 0.f, 0.f, 0.f};
  f32x4 acc3 = {0.f, 0.f, 0.f, 0.f};
#pragma unroll
  for (int kk = 0; kk < 2; ++kk) {
    bf16x8 a = *(const bf16x8*)(ap + kk * 32);
    bf16x8 b0 = *(const bf16x8*)(wp + (size_t)(kk * 4 + 0) * 512);
    bf16x8 b1 = *(const bf16x8*)(wp + (size_t)(kk * 4 + 1) * 512);
    bf16x8 b2 = *(const bf16x8*)(wp + (size_t)(kk * 4 + 2) * 512);
    bf16x8 b3 = *(const bf16x8*)(wp + (size_t)(kk * 4 + 3) * 512);
    acc0 = __builtin_amdgcn_mfma_f32_16x16x32_bf16(a, b0, acc0, 0, 0, 0);
    acc1 = __builtin_amdgcn_mfma_f32_16x16x32_bf16(a, b1, acc1, 0, 0, 0);
    acc2 = __builtin_amdgcn_mfma_f32_16x16x32_bf16(a, b2, acc2, 0, 0, 0);
    acc3 = __builtin_amdgcn_mfma_f32_16x16x32_bf16(a, b3, acc3, 0, 0, 0);
  }
  int ccol = lane & 15;
  int crow = (lane >> 4) * 4;
  float av0 = attn[ccol], av1 = attn[16 + ccol], av2 = attn[32 + ccol], av3 = attn[48 + ccol];
  float bv0 = bias[ccol], bv1 = bias[16 + ccol], bv2 = bias[32 + ccol], bv3 = bias[48 + ccol];
#pragma unroll
  for (int j = 0; j < 4; ++j) {
    int r = m0 + crow + j;
    int2 sd = sd_s[r];
    const ush* hsp = hs + (size_t)sd.x * 64;
    const ush* hdp = hd + (size_t)sd.y * 64;
    float f0 = acc0[j] + bf2f(hsp[ccol]) + bf2f(hdp[ccol]) + bv0;
    float f1 = acc1[j] + bf2f(hsp[16 + ccol]) + bf2f(hdp[16 + ccol]) + bv1;
    float f2 = acc2[j] + bf2f(hsp[32 + ccol]) + bf2f(hdp[32 + ccol]) + bv2;
    float f3 = acc3[j] + bf2f(hsp[48 + ccol]) + bf2f(hdp[48 + ccol]) + bv3;
    f0 = f0 >= 0.f ? f0 : 0.01f * f0;
    f1 = f1 >= 0.f ? f1 : 0.01f * f1;
    f2 = f2 >= 0.f ? f2 : 0.01f * f2;
    f3 = f3 >= 0.f ? f3 : 0.01f * f3;
    float p = fmaf(f0, av0, fmaf(f1, av1, fmaf(f2, av2, f3 * av3)));
    p += __shfl_xor(p, 1, 64);
    p += __shfl_xor(p, 2, 64);
    p += __shfl_xor(p, 4, 64);
    p += __shfl_xor(p, 8, 64);
    if (ccol == 0) logit[r] = p;
  }
}

// ---------------- EGAT: gather-aggregate; OSTRIDE lets layer-2 write out[] directly ------
template <bool BF16OUT, int OSTRIDE>
__global__ __launch_bounds__(256, 4) void agg_gather_kernel(
    const ush* __restrict__ hn, const float* __restrict__ logit, const int* __restrict__ rowptr,
    const int* __restrict__ deg, const int2* __restrict__ sd_s, void* __restrict__ hnew) {
  int wave = (blockIdx.x * blockDim.x + threadIdx.x) >> 6;
  int lane = threadIdx.x & 63;
  if (wave >= NN) return;
  int n = wave, d = deg[n], r0 = rowptr[n];
  if (d == 0) {
    if (BF16OUT) ((ush*)hnew)[(size_t)n * OSTRIDE + lane] = 0;
    else ((float*)hnew)[(size_t)n * OSTRIDE + lane] = 0.f;
    return;
  }
  float sum = 0.f, acc0 = 0.f, acc1 = 0.f, acc2 = 0.f, acc3 = 0.f;
  int j = 0;
  for (; j + 3 < d; j += 4) {
    int jj = r0 + j;
    int s0 = sd_s[jj + 0].x, s1 = sd_s[jj + 1].x, s2 = sd_s[jj + 2].x, s3 = sd_s[jj + 3].x;
    float l0 = logit[jj + 0], l1 = logit[jj + 1], l2 = logit[jj + 2], l3 = logit[jj + 3];
    ush h0 = hn[(size_t)s0 * 64 + lane];
    ush h1 = hn[(size_t)s1 * 64 + lane];
    ush h2 = hn[(size_t)s2 * 64 + lane];
    ush h3 = hn[(size_t)s3 * 64 + lane];
    float w0 = __expf(l0), w1 = __expf(l1);
    float w2 = __expf(l2), w3 = __expf(l3);
    sum += (w0 + w1) + (w2 + w3);
    acc0 = fmaf(w0, bf2f(h0), acc0);
    acc1 = fmaf(w1, bf2f(h1), acc1);
    acc2 = fmaf(w2, bf2f(h2), acc2);
    acc3 = fmaf(w3, bf2f(h3), acc3);
  }
  for (; j < d; ++j) {
    int jj = r0 + j;
    float w = __expf(logit[jj]);
    sum += w;
    acc0 = fmaf(w, bf2f(hn[(size_t)sd_s[jj].x * 64 + lane]), acc0);
  }
  float r = ((acc0 + acc1) + (acc2 + acc3)) / sum;
  if (BF16OUT) ((ush*)hnew)[(size_t)n * OSTRIDE + lane] = f2bf(r);
  else ((float*)hnew)[(size_t)n * OSTRIDE + lane] = r;
}

// ---------------- NNConv fused: gather G into LDS, MFMA GEMM from LDS, fused combine -----
// Phase 1: 4 waves gather 16 nodes' G rows into Gs. Phase 2: waves 0,1 MFMA -> sA (LDS).
// Phase 3: each wave combines its 4 nodes: v1 = sA/deg + bias -> out[:,64:96], gate dot -> g.
__global__ __launch_bounds__(256, 4) void nnconv_fused_kernel(
    const ush* __restrict__ face16, const ush* __restrict__ ef16,
    const int* __restrict__ rowptr, const int* __restrict__ deg,
    const int2* __restrict__ sd_s, const ush* __restrict__ Wfrag,
    const float* __restrict__ nn_bias, const float* __restrict__ gate_w,
    const float* __restrict__ gate_b, float* __restrict__ out, float* __restrict__ g) {
  __shared__ ush Gs[16][552];
  __shared__ float sA[16][32];
  int wid = threadIdx.x >> 6;
  int lane = threadIdx.x & 63;
  int nbase = blockIdx.x * 16;  // NN % 16 == 0
  int k4 = lane >> 2, ib = lane & 3;
  for (int q = 0; q < 4; ++q) {
    int row = wid * 4 + q;
    int n = nbase + row;
    int d = deg[n], r0 = rowptr[n];
    float gr[8], fs[8];
#pragma unroll
    for (int u = 0; u < 8; ++u) { gr[u] = 0.f; fs[u] = 0.f; }
    int j = 0;
    for (; j + 1 < d; j += 2) {
      int jj = r0 + j;
      int s0 = sd_s[jj].x, s1 = sd_s[jj + 1].x;
      float ev0 = bf2f(ef16[(size_t)jj * 16 + k4]);
      float ev1 = bf2f(ef16[(size_t)(jj + 1) * 16 + k4]);
      uint4 u0 = *(const uint4*)(face16 + (size_t)s0 * 32 + ib * 8);
      uint4 u1 = *(const uint4*)(face16 + (size_t)s1 * 32 + ib * 8);
      float fa0[8], fa1[8];
      unp8(u0, fa0);
      unp8(u1, fa1);
#pragma unroll
      for (int u = 0; u < 8; ++u) {
        gr[u] = fmaf(ev0, fa0[u], gr[u]);
        gr[u] = fmaf(ev1, fa1[u], gr[u]);
      }
      if (k4 == 0) {
#pragma unroll
        for (int u = 0; u < 8; ++u) fs[u] += fa0[u] + fa1[u];
      }
    }
    if (j < d) {
      int jj = r0 + j;
      float ev0 = bf2f(ef16[(size_t)jj * 16 + k4]);
      uint4 u0 = *(const uint4*)(face16 + (size_t)sd_s[jj].x * 32 + ib * 8);
      float fa0[8];
      unp8(u0, fa0);
#pragma unroll
      for (int u = 0; u < 8; ++u) gr[u] = fmaf(ev0, fa0[u], gr[u]);
      if (k4 == 0) {
#pragma unroll
        for (int u = 0; u < 8; ++u) fs[u] += fa0[u];
      }
    }
    uint4 pv;
    pv.x = pack2(gr[0], gr[1]); pv.y = pack2(gr[2], gr[3]);
    pv.z = pack2(gr[4], gr[5]); pv.w = pack2(gr[6], gr[7]);
    *(uint4*)&Gs[row][lane * 8] = pv;
    if (k4 == 0) {
      uint4 fv;
      fv.x = pack2(fs[0], fs[1]); fv.y = pack2(fs[2], fs[3]);
      fv.z = pack2(fs[4], fs[5]); fv.w = pack2(fs[6], fs[7]);
      *(uint4*)&Gs[row][512 + ib * 8] = fv;
    }
  }
  __syncthreads();
  if (wid < 2) {
    int arow = lane & 15;
    int aoff = (lane >> 4) * 8;
    const ush* wp = Wfrag + lane * 8;
    f32x4 acc = {0.f, 0.f, 0.f, 0.f};
#pragma unroll 4
    for (int kk = 0; kk < 17; ++kk) {
      bf16x8 a = *(const bf16x8*)&Gs[arow][kk * 32 + aoff];
      bf16x8 b = *(const bf16x8*)(wp + (size_t)(kk * 2 + wid) * 512);
      acc = __builtin_amdgcn_mfma_f32_16x16x32_bf16(a, b, acc, 0, 0, 0);
    }
    int ccol = lane & 15;
    int crow = (lane >> 4) * 4;
#pragma unroll
    for (int j = 0; j < 4; ++j) {
      sA[crow + j][wid * 16 + ccol] = acc[j];
    }
  }
  __syncthreads();
  // fused combine + gate logit for this block's 16 nodes
  float gb = gate_b[0];
  float gw0 = gate_w[lane];
  int c1 = lane + 64;
  float gw1 = (c1 < 96) ? gate_w[c1] : 0.f;
  float nb = (c1 < 96) ? nn_bias[c1 - 64] : 0.f;
#pragma unroll
  for (int q = 0; q < 4; ++q) {
    int row = wid * 4 + q;
    int n = nbase + row;
    float v0 = out[(size_t)n * 128 + lane];
    float v1 = (c1 < 96) ? sA[row][c1 - 64] / fmaxf((float)deg[n], 1.0f) + nb : 0.f;
    out[(size_t)n * 128 + c1] = v1;
    float p = v0 * gw0 + v1 * gw1;
#pragma unroll
    for (int off = 32; off; off >>= 1) p += __shfl_xor(p, off, 64);
    if (lane == 0) g[n] = p + gb;
  }
}

// ---------------- max over g (block-reduced, 1 atomic per block; 128 blocks) ----------------
__global__ void gate_max_kernel(const float* __restrict__ g, unsigned* __restrict__ gmax) {
  int tid = blockIdx.x * blockDim.x + threadIdx.x;
  int stride = gridDim.x * blockDim.x;
  float v = -3.0e38f;
  for (int n = tid; n < NN; n += stride) v = fmaxf(v, g[n]);
#pragma unroll
  for (int off = 32; off; off >>= 1) v = fmaxf(v, __shfl_xor(v, off, 64));
  __shared__ float sm[4];
  int lane = threadIdx.x & 63, wid = threadIdx.x >> 6;
  if (lane == 0) sm[wid] = v;
  __syncthreads();
  if (threadIdx.x == 0) {
    float m = fmaxf(fmaxf(sm[0], sm[1]), fmaxf(sm[2], sm[3]));
    atomicMax(gmax, ord_enc(m));
  }
}

// ---------------- pooling: exp + weighted accumulate; 4-deep ILP ----------------
__global__ __launch_bounds__(256, 4) void pool_exp_kernel(
    const float* __restrict__ nf, const float* __restrict__ g, const unsigned* __restrict__ gmax,
    float* __restrict__ pacc, float* __restrict__ wsb) {
  int o = threadIdx.x & 127;
  int half = threadIdx.x >> 7;
  int ri = blockIdx.x * 2 + half;   // 0 .. 2*PB-1
  float m = ord_dec(*gmax);
  float acc0 = 0.f, acc1 = 0.f, acc2 = 0.f, acc3 = 0.f, ws = 0.f;
  const int STR = PB * 2;
  int n = ri;
  for (; n + 3 * STR < NN; n += 4 * STR) {
    float w0 = __expf(g[n] - m);
    float w1 = __expf(g[n + STR] - m);
    float w2 = __expf(g[n + 2 * STR] - m);
    float w3 = __expf(g[n + 3 * STR] - m);
    float v0 = nf[(size_t)n * 128 + o];
    float v1 = nf[(size_t)(n + STR) * 128 + o];
    float v2 = nf[(size_t)(n + 2 * STR) * 128 + o];
    float v3 = nf[(size_t)(n + 3 * STR) * 128 + o];
    ws += (w0 + w1) + (w2 + w3);
    acc0 = fmaf(w0, v0, acc0);
    acc1 = fmaf(w1, v1, acc1);
    acc2 = fmaf(w2, v2, acc2);
    acc3 = fmaf(w3, v3, acc3);
  }
  for (; n < NN; n += STR) {
    float w = __expf(g[n] - m);
    ws += w;
    acc0 = fmaf(w, nf[(size_t)n * 128 + o], acc0);
  }
  pacc[(size_t)ri * 128 + o] = (acc0 + acc1) + (acc2 + acc3);
  if (o == 0) wsb[ri] = ws;
}

// reduce partials + finalize: 128 blocks; block b sums pacc column b AND wsb, writes out.
__global__ void pool_reduce_kernel(const float* __restrict__ pacc, const float* __restrict__ wsb,
                                   float* __restrict__ out) {
  int b = blockIdx.x;
  int t = threadIdx.x;  // 256
  float v = 0.f, w = 0.f;
  for (int ri = t; ri < PB * 2; ri += 256) {
    v += pacc[(size_t)ri * 128 + b];
    w += wsb[ri];
  }
#pragma unroll
  for (int off = 32; off; off >>= 1) {
    v += __shfl_xor(v, off, 64);
    w += __shfl_xor(w, off, 64);
  }
  __shared__ float sm[4], sw[4];
  int lane = t & 63, wid = t >> 6;
  if (lane == 0) { sm[wid] = v; sw[wid] = w; }
  __syncthreads();
  if (t == 0) {
    float s = (sm[0] + sm[1]) + (sm[2] + sm[3]);
    float wsum = (sw[0] + sw[1]) + (sw[2] + sw[3]);
    out[(size_t)NN * 128 + b] = s / wsum;
  }
}

extern "C" void kernel_launch(void* const* d_in, const int* in_sizes, int n_in,
                              void* d_out, int out_size, void* d_ws, size_t ws_size,
                              hipStream_t stream) {
  const float* face    = (const float*)d_in[0];
  const float* ef      = (const float*)d_in[1];
  const float* fp_w    = (const float*)d_in[2];
  const float* fp_b    = (const float*)d_in[3];
  const float* ep_w    = (const float*)d_in[4];
  const float* ep_b    = (const float*)d_in[5];
  const float* nn_w    = (const float*)d_in[6];
  const float* nn_b    = (const float*)d_in[7];
  const float* nn_bias = (const float*)d_in[8];
  const float* gate_w  = (const float*)d_in[9];
  const float* gate_b  = (const float*)d_in[10];
  const int*   src     = (const int*)d_in[11];
  const int*   dst     = (const int*)d_in[12];
  const float* e1_attn = (const float*)d_in[17];
  const float* e2_ni   = (const float*)d_in[19];
  const float* e2_nj   = (const float*)d_in[20];
  const float* e2_fij  = (const float*)d_in[21];
  const float* e2_attn = (const float*)d_in[23];
  const float* e2_bias = (const float*)d_in[24];
  float* out = (float*)d_out;

  char* p = (char*)d_ws;
  auto alloc = [&](size_t nfloats) {
    float* r = (float*)p;
    p += ((nfloats * 4 + 255) / 256) * 256;
    return r;
  };
  ush* h1bf = (ush*)alloc((size_t)NN * 32);   // layer-1 output (bf16)
  ush* hs16 = (ush*)alloc((size_t)NN * 32);   // NN*64 bf16
  ush* hd16 = (ush*)alloc((size_t)NN * 32);
  ush* hn16 = (ush*)alloc((size_t)NN * 32);
  ush* f116 = (ush*)alloc((size_t)NE * 32);   // NE*64 bf16 (dst-sorted order)
  float* logit = alloc(NE);                   // dst-sorted order
  float* g     = alloc(NN);
  unsigned* gmax = (unsigned*)alloc(1);
  float* fold  = alloc(7424);
  ush* Wfrag   = (ush*)alloc(17408 / 2);      // nn MFMA B-fragments
  ush* Wfrag2  = (ush*)alloc(4096 / 2);       // e2_fij MFMA B-fragments
  ush* WfragH  = (ush*)alloc(12288 / 2);      // e2_{ni,nj,node} MFMA B-fragments
  ush* Wf1frag = (ush*)alloc(2048 / 2);       // layer-1 folded fij MFMA B-fragments
  ush* WfragH1 = (ush*)alloc(6144 / 2);       // layer-1 folded {ni,nj,node} B-fragments
  ush* face16  = (ush*)alloc((size_t)NN * 16);  // NN*32 bf16
  ush* ef16    = (ush*)alloc((size_t)NE * 8);   // NE*16 bf16 (dst-sorted, no padding)
  float* pacc  = alloc((size_t)PB * 2 * 128); // pooling partials
  float* wsb   = alloc(PB * 2);
  // dst-CSR
  int* deg    = (int*)alloc(NN);
  int* rowptr = (int*)alloc(NN);
  int* cursor = (int*)alloc(NN);
  int* partial = (int*)alloc(256);
  int2* sd_s  = (int2*)alloc((size_t)NE * 2);  // packed (src,dst), dst-sorted

  const int B = 256;
  const int NB256 = cdiv(NN, 256);

  // ---- CSR build (dst-sorted) + fused edge permutation (bf16 only) ----
  hipMemsetAsync(deg, 0, NN * 4, stream);
  deg_kernel<<<cdiv(NE, B), B, 0, stream>>>(dst, deg);
  scan1_kernel<<<NB256, 256, 0, stream>>>(deg, rowptr, partial);
  scan2_kernel<<<1, 256, 0, stream>>>(partial, NB256);
  scan3_kernel<<<NB256, 256, 0, stream>>>(rowptr, partial, cursor);
  scatter_dst_kernel<<<cdiv(NE, B), B, 0, stream>>>(src, dst, ef, cursor, sd_s, ef16);

  // ---- weight prep: fold, then merged fragment packs + face convert ----
  fold_kernel<<<29, B, 0, stream>>>(fp_w, fp_b, ep_w, ep_b,
                                    (const float*)d_in[15], (const float*)d_in[18],
                                    (const float*)d_in[13], (const float*)d_in[14],
                                    (const float*)d_in[16], fold);
  prep_rest_kernel<<<cdiv(41984 + NN * 8, B), B, 0, stream>>>(
      fold, nn_w, nn_b, e2_fij, e2_ni, e2_nj, (const float*)d_in[22], face,
      Wf1frag, WfragH1, Wfrag, Wfrag2, WfragH, face16);

  // ---- EGAT layer 1 (all matmuls on matrix cores) ----
  mfma_hproj1_kernel<<<cdiv(NN * 4, B), B, 0, stream>>>(face16, WfragH1, fold, hs16, hd16, hn16);
  mfma_fout1_kernel<<<cdiv(NE * 4, B), B, 0, stream>>>(ef16, Wf1frag, fold, hs16, hd16,
                                                       sd_s, e1_attn, f116, logit);
  agg_gather_kernel<true, 64><<<cdiv(NN * 64, B), B, 0, stream>>>(hn16, logit, rowptr, deg,
                                                                  sd_s, h1bf);

  // ---- EGAT layer 2 (hproj + edge GEMM on matrix cores) ----
  mfma_hproj_kernel<<<cdiv(NN * 4, B), B, 0, stream>>>(h1bf, WfragH, hs16, hd16, hn16);
  mfma_fout_kernel<<<cdiv(NE * 4, B), B, 0, stream>>>(f116, Wfrag2, e2_bias, hs16, hd16,
                                                      sd_s, e2_attn, logit);
  // layer-2 aggregate writes Gf directly into out[:, 0:64]
  agg_gather_kernel<false, 128><<<cdiv(NN * 64, B), B, 0, stream>>>(hn16, logit, rowptr, deg,
                                                                    sd_s, out);

  // ---- NNConv fused + combine + gate logits (G and sArr live only in LDS) ----
  nnconv_fused_kernel<<<NN / 16, B, 0, stream>>>(face16, ef16, rowptr, deg, sd_s, Wfrag,
                                                 nn_bias, gate_w, gate_b, out, g);

  // ---- pooling ----
  hipMemsetAsync(gmax, 0, 4, stream);
  gate_max_kernel<<<128, B, 0, stream>>>(g, gmax);
  pool_exp_kernel<<<PB, B, 0, stream>>>(out, g, gmax, pacc, wsb);
  pool_reduce_kernel<<<128, B, 0, stream>>>(pacc, wsb, out);
}

// Round 31
// 228.255 us; speedup vs baseline: 1.7170x; 1.0071x over previous
//
#include <hip/hip_runtime.h>

#define NN 60000
#define NE 300000
#define PB 768
typedef unsigned short ush;
typedef __attribute__((ext_vector_type(8))) short bf16x8;
typedef __attribute__((ext_vector_type(4))) float f32x4;

static inline int cdiv(int a, int b) { return (a + b - 1) / b; }

__device__ inline unsigned ord_enc(float x) {
  unsigned u = __float_as_uint(x);
  return (u & 0x80000000u) ? ~u : (u | 0x80000000u);
}
__device__ inline float ord_dec(unsigned u) {
  return __uint_as_float((u & 0x80000000u) ? (u & 0x7fffffffu) : ~u);
}
__device__ inline float bf2f(unsigned u16) { return __uint_as_float(u16 << 16); }
__device__ inline ush f2bf(float x) {
  unsigned u = __float_as_uint(x);
  return (ush)((u + 0x7FFFu + ((u >> 16) & 1u)) >> 16);
}
__device__ inline unsigned pack2(float lo, float hi) {
  return ((unsigned)f2bf(hi) << 16) | (unsigned)f2bf(lo);
}
__device__ inline void unp8(uint4 u, float* f) {
  f[0] = bf2f(u.x & 0xffff); f[1] = bf2f(u.x >> 16);
  f[2] = bf2f(u.y & 0xffff); f[3] = bf2f(u.y >> 16);
  f[4] = bf2f(u.z & 0xffff); f[5] = bf2f(u.z >> 16);
  f[6] = bf2f(u.w & 0xffff); f[7] = bf2f(u.w >> 16);
}

// ================= CSR build (dst-sorted) =================
__global__ void deg_kernel(const int* __restrict__ key, int* __restrict__ deg) {
  int e = blockIdx.x * blockDim.x + threadIdx.x;
  if (e < NE) atomicAdd(deg + key[e], 1);
}

__global__ void scan1_kernel(const int* __restrict__ deg, int* __restrict__ rowptr,
                             int* __restrict__ partial) {
  __shared__ int s[256];
  int i = blockIdx.x * 256 + threadIdx.x;
  int v = (i < NN) ? deg[i] : 0;
  s[threadIdx.x] = v;
  __syncthreads();
  for (int off = 1; off < 256; off <<= 1) {
    int t = (threadIdx.x >= off) ? s[threadIdx.x - off] : 0;
    __syncthreads();
    s[threadIdx.x] += t;
    __syncthreads();
  }
  if (i < NN) rowptr[i] = s[threadIdx.x] - v;
  if (threadIdx.x == 255) partial[blockIdx.x] = s[255];
}

__global__ void scan2_kernel(int* __restrict__ partial, int nb) {
  __shared__ int s[256];
  int v = (threadIdx.x < nb) ? partial[threadIdx.x] : 0;
  s[threadIdx.x] = v;
  __syncthreads();
  for (int off = 1; off < 256; off <<= 1) {
    int t = (threadIdx.x >= off) ? s[threadIdx.x - off] : 0;
    __syncthreads();
    s[threadIdx.x] += t;
    __syncthreads();
  }
  if (threadIdx.x < nb) partial[threadIdx.x] = s[threadIdx.x] - v;
}

__global__ void scan3_kernel(int* __restrict__ rowptr, const int* __restrict__ partial,
                             int* __restrict__ cursor) {
  int i = blockIdx.x * 256 + threadIdx.x;
  if (i < NN) {
    int r = rowptr[i] + partial[blockIdx.x];
    rowptr[i] = r;
    cursor[i] = r;
  }
}

// scatter + ef permutation fused; emits ef16 (NEx16 bf16) + packed (src,dst) int2
__global__ void scatter_dst_kernel(const int* __restrict__ src, const int* __restrict__ dst,
                                   const float* __restrict__ ef, int* __restrict__ cursor,
                                   int2* __restrict__ sd_s, ush* __restrict__ ef16) {
  int e = blockIdx.x * blockDim.x + threadIdx.x;
  if (e >= NE) return;
  int d = dst[e];
  int j = atomicAdd(cursor + d, 1);
  sd_s[j] = make_int2(src[e], d);
  const float4* ep = (const float4*)(ef + (size_t)e * 16);
  float4 a = ep[0], b = ep[1], c = ep[2], dd = ep[3];
  uint4* bp = (uint4*)(ef16 + (size_t)j * 16);
  uint4 p0, p1;
  p0.x = pack2(a.x, a.y); p0.y = pack2(a.z, a.w);
  p0.z = pack2(b.x, b.y); p0.w = pack2(b.z, b.w);
  p1.x = pack2(c.x, c.y); p1.y = pack2(c.z, c.w);
  p1.z = pack2(dd.x, dd.y); p1.w = pack2(dd.z, dd.w);
  bp[0] = p0; bp[1] = p1;
}

// ---------------- fold: precompute folded weight products (7424 dots of length 64) -------
__global__ void fold_kernel(const float* __restrict__ fp_w, const float* __restrict__ fp_b,
                            const float* __restrict__ ep_w, const float* __restrict__ ep_b,
                            const float* __restrict__ fij, const float* __restrict__ ebias,
                            const float* __restrict__ ni, const float* __restrict__ nj,
                            const float* __restrict__ node, float* __restrict__ fold) {
  int t = blockIdx.x * blockDim.x + threadIdx.x;
  if (t >= 7424) return;
  int o = t & 63;
  const float* A;
  const float* B;
  float init = 0.f;
  if (t < 1024)      { A = ep_w + (size_t)(t >> 6) * 64; B = fij + o; }
  else if (t < 1088) { A = ep_b; B = fij + o; init = ebias[o]; }
  else if (t < 3136) { A = fp_w + (size_t)((t - 1088) >> 6) * 64; B = ni + o; }
  else if (t < 5184) { A = fp_w + (size_t)((t - 3136) >> 6) * 64; B = nj + o; }
  else if (t < 7232) { A = fp_w + (size_t)((t - 5184) >> 6) * 64; B = node + o; }
  else if (t < 7296) { A = fp_b; B = ni + o; }
  else if (t < 7360) { A = fp_b; B = nj + o; }
  else               { A = fp_b; B = node + o; }
  float a = init;
  for (int i = 0; i < 64; ++i) a = fmaf(A[i], B[(size_t)i * 64], a);
  fold[t] = a;
}

// ---------------- merged prep: fold1_frag | nnwt | fij | hproj_frag | face16 -------------
__global__ void prep_rest_kernel(const float* __restrict__ fold, const float* __restrict__ nn_w,
                                 const float* __restrict__ nn_b, const float* __restrict__ fij,
                                 const float* __restrict__ ni, const float* __restrict__ nj,
                                 const float* __restrict__ node, const float* __restrict__ face,
                                 ush* __restrict__ Wf1frag, ush* __restrict__ WfragH1,
                                 ush* __restrict__ Wfrag, ush* __restrict__ Wfrag2,
                                 ush* __restrict__ WfragH, ush* __restrict__ face16) {
  int t = blockIdx.x * blockDim.x + threadIdx.x;
  if (t < 8192) {
    if (t < 2048) {
      int i = t & 7, lane = (t >> 3) & 63, ct = t >> 9;
      int k = (lane >> 4) * 8 + i;
      int o = ct * 16 + (lane & 15);
      Wf1frag[t] = (k < 16) ? f2bf(fold[(size_t)k * 64 + o]) : 0;
    } else {
      int idx = t - 2048;
      int i = idx & 7, lane = (idx >> 3) & 63, ct = (idx >> 9) & 3, m = idx >> 11;
      int k = (lane >> 4) * 8 + i;
      int o = ct * 16 + (lane & 15);
      WfragH1[idx] = f2bf(fold[1088 + (size_t)m * 2048 + (size_t)k * 64 + o]);
    }
  } else if (t < 25600) {
    int u = t - 8192;
    int i = u & 7, lane = (u >> 3) & 63, ct = (u >> 9) & 1, kk = u >> 10;
    int k = kk * 32 + (lane >> 4) * 8 + i;
    int o = ct * 16 + (lane & 15);
    float v = (k < 512) ? nn_w[(size_t)(k >> 5) * 1024 + (k & 31) * 32 + o]
                        : nn_b[(k - 512) * 32 + o];
    Wfrag[u] = f2bf(v);
  } else if (t < 29696) {
    int u = t - 25600;
    int i = u & 7, lane = (u >> 3) & 63, ct = (u >> 9) & 3, kk = u >> 11;
    int k = kk * 32 + (lane >> 4) * 8 + i;
    int o = ct * 16 + (lane & 15);
    Wfrag2[u] = f2bf(fij[(size_t)k * 64 + o]);
  } else if (t < 41984) {
    int u = t - 29696;
    int i = u & 7, lane = (u >> 3) & 63, ct = (u >> 9) & 3, kk = (u >> 11) & 1, m = u >> 12;
    int k = kk * 32 + (lane >> 4) * 8 + i;
    int o = ct * 16 + (lane & 15);
    const float* W = (m == 0) ? ni : (m == 1) ? nj : node;
    WfragH[u] = f2bf(W[(size_t)k * 64 + o]);
  } else if (t < 41984 + NN * 8) {
    int u = t - 41984;
    const float4 v = ((const float4*)face)[u];
    ((uint2*)face16)[u] = make_uint2(pack2(v.x, v.y), pack2(v.z, v.w));
  }
}

// ---------------- layer-1 hproj via MFMA: face16(NNx32) @ folded {ni,nj,node}(32x64) -----
__global__ __launch_bounds__(256, 4) void mfma_hproj1_kernel(
    const ush* __restrict__ face16, const ush* __restrict__ WfragH1,
    const float* __restrict__ fold, ush* __restrict__ hs, ush* __restrict__ hd,
    ush* __restrict__ hn) {
  int wave = (blockIdx.x * blockDim.x + threadIdx.x) >> 6;
  int lane = threadIdx.x & 63;
  int m0 = wave * 16;
  if (m0 >= NN) return;
  int arow = lane & 15;
  int aoff = (lane >> 4) * 8;
  bf16x8 a = *(const bf16x8*)(face16 + (size_t)(m0 + arow) * 32 + aoff);
  int ccol = lane & 15;
  int crow = (lane >> 4) * 4;
#pragma unroll
  for (int m = 0; m < 3; ++m) {
    const ush* wm = WfragH1 + (size_t)m * 2048 + lane * 8;
    bf16x8 b0 = *(const bf16x8*)(wm + 0 * 512);
    bf16x8 b1 = *(const bf16x8*)(wm + 1 * 512);
    bf16x8 b2 = *(const bf16x8*)(wm + 2 * 512);
    bf16x8 b3 = *(const bf16x8*)(wm + 3 * 512);
    f32x4 acc0 = {0.f, 0.f, 0.f, 0.f};
    f32x4 acc1 = {0.f, 0.f, 0.f, 0.f};
    f32x4 acc2 = {0.f, 0.f, 0.f, 0.f};
    f32x4 acc3 = {0.f, 0.f, 0.f, 0.f};
    acc0 = __builtin_amdgcn_mfma_f32_16x16x32_bf16(a, b0, acc0, 0, 0, 0);
    acc1 = __builtin_amdgcn_mfma_f32_16x16x32_bf16(a, b1, acc1, 0, 0, 0);
    acc2 = __builtin_amdgcn_mfma_f32_16x16x32_bf16(a, b2, acc2, 0, 0, 0);
    acc3 = __builtin_amdgcn_mfma_f32_16x16x32_bf16(a, b3, acc3, 0, 0, 0);
    float bv0 = fold[7232 + m * 64 + ccol];
    float bv1 = fold[7232 + m * 64 + 16 + ccol];
    float bv2 = fold[7232 + m * 64 + 32 + ccol];
    float bv3 = fold[7232 + m * 64 + 48 + ccol];
    ush* outm = (m == 0) ? hs : (m == 1) ? hd : hn;
#pragma unroll
    for (int j = 0; j < 4; ++j) {
      ush* op = outm + (size_t)(m0 + crow + j) * 64;
      op[ccol] = f2bf(acc0[j] + bv0);
      op[16 + ccol] = f2bf(acc1[j] + bv1);
      op[32 + ccol] = f2bf(acc2[j] + bv2);
      op[48 + ccol] = f2bf(acc3[j] + bv3);
    }
  }
}

// ---------------- layer-1 edge GEMM via MFMA: ef16(NEx16) @ Wf1(32x64, folded, k>=16 = 0) -
__global__ __launch_bounds__(256, 4) void mfma_fout1_kernel(
    const ush* __restrict__ ef16, const ush* __restrict__ Wf1frag, const float* __restrict__ fold,
    const ush* __restrict__ hs, const ush* __restrict__ hd, const int2* __restrict__ sd_s,
    const float* __restrict__ attn, ush* __restrict__ f116, float* __restrict__ logit) {
  int wave = (blockIdx.x * blockDim.x + threadIdx.x) >> 6;
  int lane = threadIdx.x & 63;
  int m0 = wave * 16;
  if (m0 >= NE) return;
  int arow = lane & 15;
  int aoff = (lane >> 4) * 8;
  bf16x8 a = {0, 0, 0, 0, 0, 0, 0, 0};
  if (aoff < 16) a = *(const bf16x8*)(ef16 + (size_t)(m0 + arow) * 16 + aoff);
  const ush* wp = Wf1frag + lane * 8;
  bf16x8 b0 = *(const bf16x8*)(wp + 0 * 512);
  bf16x8 b1 = *(const bf16x8*)(wp + 1 * 512);
  bf16x8 b2 = *(const bf16x8*)(wp + 2 * 512);
  bf16x8 b3 = *(const bf16x8*)(wp + 3 * 512);
  f32x4 acc0 = {0.f, 0.f, 0.f, 0.f};
  f32x4 acc1 = {0.f, 0.f, 0.f, 0.f};
  f32x4 acc2 = {0.f, 0.f, 0.f, 0.f};
  f32x4 acc3 = {0.f, 0.f, 0.f, 0.f};
  acc0 = __builtin_amdgcn_mfma_f32_16x16x32_bf16(a, b0, acc0, 0, 0, 0);
  acc1 = __builtin_amdgcn_mfma_f32_16x16x32_bf16(a, b1, acc1, 0, 0, 0);
  acc2 = __builtin_amdgcn_mfma_f32_16x16x32_bf16(a, b2, acc2, 0, 0, 0);
  acc3 = __builtin_amdgcn_mfma_f32_16x16x32_bf16(a, b3, acc3, 0, 0, 0);
  int ccol = lane & 15;
  int crow = (lane >> 4) * 4;
  float av0 = attn[ccol], av1 = attn[16 + ccol], av2 = attn[32 + ccol], av3 = attn[48 + ccol];
  float bv0 = fold[1024 + ccol], bv1 = fold[1024 + 16 + ccol];
  float bv2 = fold[1024 + 32 + ccol], bv3 = fold[1024 + 48 + ccol];
#pragma unroll
  for (int j = 0; j < 4; ++j) {
    int r = m0 + crow + j;
    int2 sd = sd_s[r];
    const ush* hsp = hs + (size_t)sd.x * 64;
    const ush* hdp = hd + (size_t)sd.y * 64;
    float f0 = acc0[j] + bf2f(hsp[ccol]) + bf2f(hdp[ccol]) + bv0;
    float f1 = acc1[j] + bf2f(hsp[16 + ccol]) + bf2f(hdp[16 + ccol]) + bv1;
    float f2 = acc2[j] + bf2f(hsp[32 + ccol]) + bf2f(hdp[32 + ccol]) + bv2;
    float f3 = acc3[j] + bf2f(hsp[48 + ccol]) + bf2f(hdp[48 + ccol]) + bv3;
    f0 = f0 >= 0.f ? f0 : 0.01f * f0;
    f1 = f1 >= 0.f ? f1 : 0.01f * f1;
    f2 = f2 >= 0.f ? f2 : 0.01f * f2;
    f3 = f3 >= 0.f ? f3 : 0.01f * f3;
    ush* fp = f116 + (size_t)r * 64;
    fp[ccol] = f2bf(f0);
    fp[16 + ccol] = f2bf(f1);
    fp[32 + ccol] = f2bf(f2);
    fp[48 + ccol] = f2bf(f3);
    float p = fmaf(f0, av0, fmaf(f1, av1, fmaf(f2, av2, f3 * av3)));
    p += __shfl_xor(p, 1, 64);
    p += __shfl_xor(p, 2, 64);
    p += __shfl_xor(p, 4, 64);
    p += __shfl_xor(p, 8, 64);
    if (ccol == 0) logit[r] = p;
  }
}

// ---------------- layer-2 hproj via MFMA: h1bf(NNx64) @ {ni,nj,node}(64x64) --------------
__global__ __launch_bounds__(256, 4) void mfma_hproj_kernel(
    const ush* __restrict__ h1bf, const ush* __restrict__ WfragH, ush* __restrict__ hs,
    ush* __restrict__ hd, ush* __restrict__ hn) {
  int wave = (blockIdx.x * blockDim.x + threadIdx.x) >> 6;
  int lane = threadIdx.x & 63;
  int m0 = wave * 16;
  if (m0 >= NN) return;
  int arow = lane & 15;
  int aoff = (lane >> 4) * 8;
  const ush* ap = h1bf + (size_t)(m0 + arow) * 64 + aoff;
  bf16x8 a0 = *(const bf16x8*)(ap);
  bf16x8 a1 = *(const bf16x8*)(ap + 32);
  const ush* wp = WfragH + lane * 8;
  int ccol = lane & 15;
  int crow = (lane >> 4) * 4;
#pragma unroll
  for (int m = 0; m < 3; ++m) {
    f32x4 acc0 = {0.f, 0.f, 0.f, 0.f};
    f32x4 acc1 = {0.f, 0.f, 0.f, 0.f};
    f32x4 acc2 = {0.f, 0.f, 0.f, 0.f};
    f32x4 acc3 = {0.f, 0.f, 0.f, 0.f};
    const ush* wm = wp + (size_t)m * 8 * 512;
    bf16x8 b0 = *(const bf16x8*)(wm + 0 * 512);
    bf16x8 b1 = *(const bf16x8*)(wm + 1 * 512);
    bf16x8 b2 = *(const bf16x8*)(wm + 2 * 512);
    bf16x8 b3 = *(const bf16x8*)(wm + 3 * 512);
    acc0 = __builtin_amdgcn_mfma_f32_16x16x32_bf16(a0, b0, acc0, 0, 0, 0);
    acc1 = __builtin_amdgcn_mfma_f32_16x16x32_bf16(a0, b1, acc1, 0, 0, 0);
    acc2 = __builtin_amdgcn_mfma_f32_16x16x32_bf16(a0, b2, acc2, 0, 0, 0);
    acc3 = __builtin_amdgcn_mfma_f32_16x16x32_bf16(a0, b3, acc3, 0, 0, 0);
    b0 = *(const bf16x8*)(wm + 4 * 512);
    b1 = *(const bf16x8*)(wm + 5 * 512);
    b2 = *(const bf16x8*)(wm + 6 * 512);
    b3 = *(const bf16x8*)(wm + 7 * 512);
    acc0 = __builtin_amdgcn_mfma_f32_16x16x32_bf16(a1, b0, acc0, 0, 0, 0);
    acc1 = __builtin_amdgcn_mfma_f32_16x16x32_bf16(a1, b1, acc1, 0, 0, 0);
    acc2 = __builtin_amdgcn_mfma_f32_16x16x32_bf16(a1, b2, acc2, 0, 0, 0);
    acc3 = __builtin_amdgcn_mfma_f32_16x16x32_bf16(a1, b3, acc3, 0, 0, 0);
    ush* outm = (m == 0) ? hs : (m == 1) ? hd : hn;
#pragma unroll
    for (int j = 0; j < 4; ++j) {
      ush* op = outm + (size_t)(m0 + crow + j) * 64;
      op[ccol] = f2bf(acc0[j]);
      op[16 + ccol] = f2bf(acc1[j]);
      op[32 + ccol] = f2bf(acc2[j]);
      op[48 + ccol] = f2bf(acc3[j]);
    }
  }
}

// ---------------- layer-2 edge GEMM via MFMA: f116(NEx64 bf16) @ fij(64x64) --------------
__global__ __launch_bounds__(256, 4) void mfma_fout_kernel(
    const ush* __restrict__ f116, const ush* __restrict__ Wfrag2, const float* __restrict__ bias,
    const ush* __restrict__ hs, const ush* __restrict__ hd, const int2* __restrict__ sd_s,
    const float* __restrict__ attn, float* __restrict__ logit) {
  int wave = (blockIdx.x * blockDim.x + threadIdx.x) >> 6;
  int lane = threadIdx.x & 63;
  int m0 = wave * 16;
  if (m0 >= NE) return;
  int arow = lane & 15;
  int aoff = (lane >> 4) * 8;
  const ush* ap = f116 + (size_t)(m0 + arow) * 64 + aoff;
  const ush* wp = Wfrag2 + lane * 8;
  f32x4 acc0 = {0.f, 0.f, 0.f, 0.f};
  f32x4 acc1 = {0.f, 0.f, 0.f, 0.f};
  f32x4 acc2 = {0.f, 0.f, 0.f, 0.f};
  f32x4 acc3 = {0.f, 0.f, 0.f, 0.f};
#pragma unroll
  for (int kk = 0; kk < 2; ++kk) {
    bf16x8 a = *(const bf16x8*)(ap + kk * 32);
    bf16x8 b0 = *(const bf16x8*)(wp + (size_t)(kk * 4 + 0) * 512);
    bf16x8 b1 = *(const bf16x8*)(wp + (size_t)(kk * 4 + 1) * 512);
    bf16x8 b2 = *(const bf16x8*)(wp + (size_t)(kk * 4 + 2) * 512);
    bf16x8 b3 = *(const bf16x8*)(wp + (size_t)(kk * 4 + 3) * 512);
    acc0 = __builtin_amdgcn_mfma_f32_16x16x32_bf16(a, b0, acc0, 0, 0, 0);
    acc1 = __builtin_amdgcn_mfma_f32_16x16x32_bf16(a, b1, acc1, 0, 0, 0);
    acc2 = __builtin_amdgcn_mfma_f32_16x16x32_bf16(a, b2, acc2, 0, 0, 0);
    acc3 = __builtin_amdgcn_mfma_f32_16x16x32_bf16(a, b3, acc3, 0, 0, 0);
  }
  int ccol = lane & 15;
  int crow = (lane >> 4) * 4;
  float av0 = attn[ccol], av1 = attn[16 + ccol], av2 = attn[32 + ccol], av3 = attn[48 + ccol];
  float bv0 = bias[ccol], bv1 = bias[16 + ccol], bv2 = bias[32 + ccol], bv3 = bias[48 + ccol];
#pragma unroll
  for (int j = 0; j < 4; ++j) {
    int r = m0 + crow + j;
    int2 sd = sd_s[r];
    const ush* hsp = hs + (size_t)sd.x * 64;
    const ush* hdp = hd + (size_t)sd.y * 64;
    float f0 = acc0[j] + bf2f(hsp[ccol]) + bf2f(hdp[ccol]) + bv0;
    float f1 = acc1[j] + bf2f(hsp[16 + ccol]) + bf2f(hdp[16 + ccol]) + bv1;
    float f2 = acc2[j] + bf2f(hsp[32 + ccol]) + bf2f(hdp[32 + ccol]) + bv2;
    float f3 = acc3[j] + bf2f(hsp[48 + ccol]) + bf2f(hdp[48 + ccol]) + bv3;
    f0 = f0 >= 0.f ? f0 : 0.01f * f0;
    f1 = f1 >= 0.f ? f1 : 0.01f * f1;
    f2 = f2 >= 0.f ? f2 : 0.01f * f2;
    f3 = f3 >= 0.f ? f3 : 0.01f * f3;
    float p = fmaf(f0, av0, fmaf(f1, av1, fmaf(f2, av2, f3 * av3)));
    p += __shfl_xor(p, 1, 64);
    p += __shfl_xor(p, 2, 64);
    p += __shfl_xor(p, 4, 64);
    p += __shfl_xor(p, 8, 64);
    if (ccol == 0) logit[r] = p;
  }
}

// ---------------- EGAT: gather-aggregate; OSTRIDE lets layer-2 write out[] directly ------
template <bool BF16OUT, int OSTRIDE>
__global__ __launch_bounds__(256, 4) void agg_gather_kernel(
    const ush* __restrict__ hn, const float* __restrict__ logit, const int* __restrict__ rowptr,
    const int* __restrict__ deg, const int2* __restrict__ sd_s, void* __restrict__ hnew) {
  int wave = (blockIdx.x * blockDim.x + threadIdx.x) >> 6;
  int lane = threadIdx.x & 63;
  if (wave >= NN) return;
  int n = wave, d = deg[n], r0 = rowptr[n];
  if (d == 0) {
    if (BF16OUT) ((ush*)hnew)[(size_t)n * OSTRIDE + lane] = 0;
    else ((float*)hnew)[(size_t)n * OSTRIDE + lane] = 0.f;
    return;
  }
  float sum = 0.f, acc0 = 0.f, acc1 = 0.f, acc2 = 0.f, acc3 = 0.f;
  int j = 0;
  for (; j + 3 < d; j += 4) {
    int jj = r0 + j;
    int s0 = sd_s[jj + 0].x, s1 = sd_s[jj + 1].x, s2 = sd_s[jj + 2].x, s3 = sd_s[jj + 3].x;
    float l0 = logit[jj + 0], l1 = logit[jj + 1], l2 = logit[jj + 2], l3 = logit[jj + 3];
    ush h0 = hn[(size_t)s0 * 64 + lane];
    ush h1 = hn[(size_t)s1 * 64 + lane];
    ush h2 = hn[(size_t)s2 * 64 + lane];
    ush h3 = hn[(size_t)s3 * 64 + lane];
    float w0 = __expf(l0), w1 = __expf(l1);
    float w2 = __expf(l2), w3 = __expf(l3);
    sum += (w0 + w1) + (w2 + w3);
    acc0 = fmaf(w0, bf2f(h0), acc0);
    acc1 = fmaf(w1, bf2f(h1), acc1);
    acc2 = fmaf(w2, bf2f(h2), acc2);
    acc3 = fmaf(w3, bf2f(h3), acc3);
  }
  for (; j < d; ++j) {
    int jj = r0 + j;
    float w = __expf(logit[jj]);
    sum += w;
    acc0 = fmaf(w, bf2f(hn[(size_t)sd_s[jj].x * 64 + lane]), acc0);
  }
  float r = ((acc0 + acc1) + (acc2 + acc3)) / sum;
  if (BF16OUT) ((ush*)hnew)[(size_t)n * OSTRIDE + lane] = f2bf(r);
  else ((float*)hnew)[(size_t)n * OSTRIDE + lane] = r;
}

// ---------------- NNConv fused: gather G into LDS, MFMA GEMM from LDS -> sArr ------------
__global__ __launch_bounds__(256, 4) void nnconv_fused_kernel(
    const ush* __restrict__ face16, const ush* __restrict__ ef16,
    const int* __restrict__ rowptr, const int* __restrict__ deg,
    const int2* __restrict__ sd_s, const ush* __restrict__ Wfrag,
    float* __restrict__ sArr) {
  __shared__ ush Gs[16][552];
  int wid = threadIdx.x >> 6;
  int lane = threadIdx.x & 63;
  int nbase = blockIdx.x * 16;  // NN % 16 == 0
  int k4 = lane >> 2, ib = lane & 3;
  for (int q = 0; q < 4; ++q) {
    int row = wid * 4 + q;
    int n = nbase + row;
    int d = deg[n], r0 = rowptr[n];
    float gr[8], fs[8];
#pragma unroll
    for (int u = 0; u < 8; ++u) { gr[u] = 0.f; fs[u] = 0.f; }
    int j = 0;
    for (; j + 1 < d; j += 2) {
      int jj = r0 + j;
      int s0 = sd_s[jj].x, s1 = sd_s[jj + 1].x;
      float ev0 = bf2f(ef16[(size_t)jj * 16 + k4]);
      float ev1 = bf2f(ef16[(size_t)(jj + 1) * 16 + k4]);
      uint4 u0 = *(const uint4*)(face16 + (size_t)s0 * 32 + ib * 8);
      uint4 u1 = *(const uint4*)(face16 + (size_t)s1 * 32 + ib * 8);
      float fa0[8], fa1[8];
      unp8(u0, fa0);
      unp8(u1, fa1);
#pragma unroll
      for (int u = 0; u < 8; ++u) {
        gr[u] = fmaf(ev0, fa0[u], gr[u]);
        gr[u] = fmaf(ev1, fa1[u], gr[u]);
      }
      if (k4 == 0) {
#pragma unroll
        for (int u = 0; u < 8; ++u) fs[u] += fa0[u] + fa1[u];
      }
    }
    if (j < d) {
      int jj = r0 + j;
      float ev0 = bf2f(ef16[(size_t)jj * 16 + k4]);
      uint4 u0 = *(const uint4*)(face16 + (size_t)sd_s[jj].x * 32 + ib * 8);
      float fa0[8];
      unp8(u0, fa0);
#pragma unroll
      for (int u = 0; u < 8; ++u) gr[u] = fmaf(ev0, fa0[u], gr[u]);
      if (k4 == 0) {
#pragma unroll
        for (int u = 0; u < 8; ++u) fs[u] += fa0[u];
      }
    }
    uint4 pv;
    pv.x = pack2(gr[0], gr[1]); pv.y = pack2(gr[2], gr[3]);
    pv.z = pack2(gr[4], gr[5]); pv.w = pack2(gr[6], gr[7]);
    *(uint4*)&Gs[row][lane * 8] = pv;
    if (k4 == 0) {
      uint4 fv;
      fv.x = pack2(fs[0], fs[1]); fv.y = pack2(fs[2], fs[3]);
      fv.z = pack2(fs[4], fs[5]); fv.w = pack2(fs[6], fs[7]);
      *(uint4*)&Gs[row][512 + ib * 8] = fv;
    }
  }
  __syncthreads();
  if (wid < 2) {
    int arow = lane & 15;
    int aoff = (lane >> 4) * 8;
    const ush* wp = Wfrag + lane * 8;
    f32x4 acc = {0.f, 0.f, 0.f, 0.f};
#pragma unroll 4
    for (int kk = 0; kk < 17; ++kk) {
      bf16x8 a = *(const bf16x8*)&Gs[arow][kk * 32 + aoff];
      bf16x8 b = *(const bf16x8*)(wp + (size_t)(kk * 2 + wid) * 512);
      acc = __builtin_amdgcn_mfma_f32_16x16x32_bf16(a, b, acc, 0, 0, 0);
    }
    int ccol = lane & 15;
    int crow = (lane >> 4) * 4;
#pragma unroll
    for (int j = 0; j < 4; ++j) {
      int r = nbase + crow + j;
      sArr[(size_t)r * 32 + wid * 16 + ccol] = acc[j];
    }
  }
}

// ---------------- combine node_features + gate logit; v0 read back from out --------------
__global__ void combine_gate_kernel(const float* __restrict__ sArr,
                                    const int* __restrict__ deg, const float* __restrict__ nn_bias,
                                    const float* __restrict__ gate_w, const float* __restrict__ gate_b,
                                    float* __restrict__ out, float* __restrict__ g) {
  int wave = (blockIdx.x * blockDim.x + threadIdx.x) >> 6;
  int lane = threadIdx.x & 63;
  if (wave >= NN) return;
  int n = wave;
  float v0 = out[(size_t)n * 128 + lane];
  int c1 = lane + 64;
  float v1 = (c1 < 96)
                 ? sArr[(size_t)n * 32 + (c1 - 64)] / fmaxf((float)deg[n], 1.0f) + nn_bias[c1 - 64]
                 : 0.f;
  out[(size_t)n * 128 + c1] = v1;
  float p = v0 * gate_w[lane] + ((c1 < 96) ? v1 * gate_w[c1] : 0.f);
#pragma unroll
  for (int off = 32; off; off >>= 1) p += __shfl_xor(p, off, 64);
  if (lane == 0) g[n] = p + gate_b[0];
}

// ---------------- max over g (block-reduced, 1 atomic per block; 128 blocks) ----------------
__global__ void gate_max_kernel(const float* __restrict__ g, unsigned* __restrict__ gmax) {
  int tid = blockIdx.x * blockDim.x + threadIdx.x;
  int stride = gridDim.x * blockDim.x;
  float v = -3.0e38f;
  for (int n = tid; n < NN; n += stride) v = fmaxf(v, g[n]);
#pragma unroll
  for (int off = 32; off; off >>= 1) v = fmaxf(v, __shfl_xor(v, off, 64));
  __shared__ float sm[4];
  int lane = threadIdx.x & 63, wid = threadIdx.x >> 6;
  if (lane == 0) sm[wid] = v;
  __syncthreads();
  if (threadIdx.x == 0) {
    float m = fmaxf(fmaxf(sm[0], sm[1]), fmaxf(sm[2], sm[3]));
    atomicMax(gmax, ord_enc(m));
  }
}

// ---------------- pooling: exp + weighted accumulate; 4-deep ILP ----------------
__global__ __launch_bounds__(256, 4) void pool_exp_kernel(
    const float* __restrict__ nf, const float* __restrict__ g, const unsigned* __restrict__ gmax,
    float* __restrict__ pacc, float* __restrict__ wsb) {
  int o = threadIdx.x & 127;
  int half = threadIdx.x >> 7;
  int ri = blockIdx.x * 2 + half;   // 0 .. 2*PB-1
  float m = ord_dec(*gmax);
  float acc0 = 0.f, acc1 = 0.f, acc2 = 0.f, acc3 = 0.f, ws = 0.f;
  const int STR = PB * 2;
  int n = ri;
  for (; n + 3 * STR < NN; n += 4 * STR) {
    float w0 = __expf(g[n] - m);
    float w1 = __expf(g[n + STR] - m);
    float w2 = __expf(g[n + 2 * STR] - m);
    float w3 = __expf(g[n + 3 * STR] - m);
    float v0 = nf[(size_t)n * 128 + o];
    float v1 = nf[(size_t)(n + STR) * 128 + o];
    float v2 = nf[(size_t)(n + 2 * STR) * 128 + o];
    float v3 = nf[(size_t)(n + 3 * STR) * 128 + o];
    ws += (w0 + w1) + (w2 + w3);
    acc0 = fmaf(w0, v0, acc0);
    acc1 = fmaf(w1, v1, acc1);
    acc2 = fmaf(w2, v2, acc2);
    acc3 = fmaf(w3, v3, acc3);
  }
  for (; n < NN; n += STR) {
    float w = __expf(g[n] - m);
    ws += w;
    acc0 = fmaf(w, nf[(size_t)n * 128 + o], acc0);
  }
  pacc[(size_t)ri * 128 + o] = (acc0 + acc1) + (acc2 + acc3);
  if (o == 0) wsb[ri] = ws;
}

// reduce partials + finalize: 128 blocks; block b sums pacc column b AND wsb, writes out.
__global__ void pool_reduce_kernel(const float* __restrict__ pacc, const float* __restrict__ wsb,
                                   float* __restrict__ out) {
  int b = blockIdx.x;
  int t = threadIdx.x;  // 256
  float v = 0.f, w = 0.f;
  for (int ri = t; ri < PB * 2; ri += 256) {
    v += pacc[(size_t)ri * 128 + b];
    w += wsb[ri];
  }
#pragma unroll
  for (int off = 32; off; off >>= 1) {
    v += __shfl_xor(v, off, 64);
    w += __shfl_xor(w, off, 64);
  }
  __shared__ float sm[4], sw[4];
  int lane = t & 63, wid = t >> 6;
  if (lane == 0) { sm[wid] = v; sw[wid] = w; }
  __syncthreads();
  if (t == 0) {
    float s = (sm[0] + sm[1]) + (sm[2] + sm[3]);
    float wsum = (sw[0] + sw[1]) + (sw[2] + sw[3]);
    out[(size_t)NN * 128 + b] = s / wsum;
  }
}

extern "C" void kernel_launch(void* const* d_in, const int* in_sizes, int n_in,
                              void* d_out, int out_size, void* d_ws, size_t ws_size,
                              hipStream_t stream) {
  const float* face    = (const float*)d_in[0];
  const float* ef      = (const float*)d_in[1];
  const float* fp_w    = (const float*)d_in[2];
  const float* fp_b    = (const float*)d_in[3];
  const float* ep_w    = (const float*)d_in[4];
  const float* ep_b    = (const float*)d_in[5];
  const float* nn_w    = (const float*)d_in[6];
  const float* nn_b    = (const float*)d_in[7];
  const float* nn_bias = (const float*)d_in[8];
  const float* gate_w  = (const float*)d_in[9];
  const float* gate_b  = (const float*)d_in[10];
  const int*   src     = (const int*)d_in[11];
  const int*   dst     = (const int*)d_in[12];
  const float* e1_attn = (const float*)d_in[17];
  const float* e2_ni   = (const float*)d_in[19];
  const float* e2_nj   = (const float*)d_in[20];
  const float* e2_fij  = (const float*)d_in[21];
  const float* e2_attn = (const float*)d_in[23];
  const float* e2_bias = (const float*)d_in[24];
  float* out = (float*)d_out;

  char* p = (char*)d_ws;
  auto alloc = [&](size_t nfloats) {
    float* r = (float*)p;
    p += ((nfloats * 4 + 255) / 256) * 256;
    return r;
  };
  ush* h1bf = (ush*)alloc((size_t)NN * 32);   // layer-1 output (bf16)
  ush* hs16 = (ush*)alloc((size_t)NN * 32);   // NN*64 bf16
  ush* hd16 = (ush*)alloc((size_t)NN * 32);
  ush* hn16 = (ush*)alloc((size_t)NN * 32);
  ush* f116 = (ush*)alloc((size_t)NE * 32);   // NE*64 bf16 (dst-sorted order)
  float* logit = alloc(NE);                   // dst-sorted order
  float* sArr  = alloc((size_t)NN * 32);
  float* g     = alloc(NN);
  unsigned* gmax = (unsigned*)alloc(1);
  float* fold  = alloc(7424);
  ush* Wfrag   = (ush*)alloc(17408 / 2);      // nn MFMA B-fragments
  ush* Wfrag2  = (ush*)alloc(4096 / 2);       // e2_fij MFMA B-fragments
  ush* WfragH  = (ush*)alloc(12288 / 2);      // e2_{ni,nj,node} MFMA B-fragments
  ush* Wf1frag = (ush*)alloc(2048 / 2);       // layer-1 folded fij MFMA B-fragments
  ush* WfragH1 = (ush*)alloc(6144 / 2);       // layer-1 folded {ni,nj,node} B-fragments
  ush* face16  = (ush*)alloc((size_t)NN * 16);  // NN*32 bf16
  ush* ef16    = (ush*)alloc((size_t)NE * 8);   // NE*16 bf16 (dst-sorted, no padding)
  float* pacc  = alloc((size_t)PB * 2 * 128); // pooling partials
  float* wsb   = alloc(PB * 2);
  // dst-CSR
  int* deg    = (int*)alloc(NN);
  int* rowptr = (int*)alloc(NN);
  int* cursor = (int*)alloc(NN);
  int* partial = (int*)alloc(256);
  int2* sd_s  = (int2*)alloc((size_t)NE * 2);  // packed (src,dst), dst-sorted

  const int B = 256;
  const int NB256 = cdiv(NN, 256);

  // ---- CSR build (dst-sorted) + fused edge permutation (bf16 only) ----
  hipMemsetAsync(deg, 0, NN * 4, stream);
  deg_kernel<<<cdiv(NE, B), B, 0, stream>>>(dst, deg);
  scan1_kernel<<<NB256, 256, 0, stream>>>(deg, rowptr, partial);
  scan2_kernel<<<1, 256, 0, stream>>>(partial, NB256);
  scan3_kernel<<<NB256, 256, 0, stream>>>(rowptr, partial, cursor);
  scatter_dst_kernel<<<cdiv(NE, B), B, 0, stream>>>(src, dst, ef, cursor, sd_s, ef16);

  // ---- weight prep: fold, then merged fragment packs + face convert ----
  fold_kernel<<<29, B, 0, stream>>>(fp_w, fp_b, ep_w, ep_b,
                                    (const float*)d_in[15], (const float*)d_in[18],
                                    (const float*)d_in[13], (const float*)d_in[14],
                                    (const float*)d_in[16], fold);
  prep_rest_kernel<<<cdiv(41984 + NN * 8, B), B, 0, stream>>>(
      fold, nn_w, nn_b, e2_fij, e2_ni, e2_nj, (const float*)d_in[22], face,
      Wf1frag, WfragH1, Wfrag, Wfrag2, WfragH, face16);

  // ---- EGAT layer 1 (all matmuls on matrix cores) ----
  mfma_hproj1_kernel<<<cdiv(NN * 4, B), B, 0, stream>>>(face16, WfragH1, fold, hs16, hd16, hn16);
  mfma_fout1_kernel<<<cdiv(NE * 4, B), B, 0, stream>>>(ef16, Wf1frag, fold, hs16, hd16,
                                                       sd_s, e1_attn, f116, logit);
  agg_gather_kernel<true, 64><<<cdiv(NN * 64, B), B, 0, stream>>>(hn16, logit, rowptr, deg,
                                                                  sd_s, h1bf);

  // ---- EGAT layer 2 (hproj + edge GEMM on matrix cores) ----
  mfma_hproj_kernel<<<cdiv(NN * 4, B), B, 0, stream>>>(h1bf, WfragH, hs16, hd16, hn16);
  mfma_fout_kernel<<<cdiv(NE * 4, B), B, 0, stream>>>(f116, Wfrag2, e2_bias, hs16, hd16,
                                                      sd_s, e2_attn, logit);
  // layer-2 aggregate writes Gf directly into out[:, 0:64]
  agg_gather_kernel<false, 128><<<cdiv(NN * 64, B), B, 0, stream>>>(hn16, logit, rowptr, deg,
                                                                    sd_s, out);

  // ---- NNConv fused (G lives only in LDS) -> sArr; combine separate (barrier cost) ----
  nnconv_fused_kernel<<<NN / 16, B, 0, stream>>>(face16, ef16, rowptr, deg, sd_s, Wfrag, sArr);
  combine_gate_kernel<<<cdiv(NN * 64, B), B, 0, stream>>>(sArr, deg, nn_bias, gate_w,
                                                          gate_b, out, g);

  // ---- pooling ----
  hipMemsetAsync(gmax, 0, 4, stream);
  gate_max_kernel<<<128, B, 0, stream>>>(g, gmax);
  pool_exp_kernel<<<PB, B, 0, stream>>>(out, g, gmax, pacc, wsb);
  pool_reduce_kernel<<<128, B, 0, stream>>>(pacc, wsb, out);
}